// Round 1
// baseline (178503.247 us; speedup 1.0000x reference)
//
#include <hip/hip_runtime.h>

#define T_STEPS 2048
#define BATCH   256
#define NXX     128
#define NYY     64
#define NUU     32
#define NDD     16

#define CCH     64
#define NCH     (T_STEPS / CCH)   // 32 chunks

// XOR swizzle: conflict-free LDS for row- and column-pattern access.
#define SWZ(i, j) (((i) << 6) + ((j) ^ ((i) & 31)))

// For row `row`, aligned col-group cg (cg%4==0): the 4 swizzled elements
// [row][cg..cg+3] live in ONE contiguous aligned float4 at
//   base = (row<<6) + (cg ^ (row&28)),
// with element (cg+b) at component (b ^ (row&3)).  (Compile-time perm when
// the k-loop is unrolled mod 4.)
__device__ __forceinline__ float4 ld4swz(const float* s, int row, int cg) {
  return *(const float4*)(s + (row << 6) + (cg ^ (row & 28)));
}
__device__ __forceinline__ void st4swz(float* s, int row, int cg, const float4& v) {
  *(float4*)(s + (row << 6) + (cg ^ (row & 28))) = v;
}

// 64x64 Gauss-Jordan inversion in place on swizzled sS (sCol = 64-float scratch).
__device__ __forceinline__ void gj64(float* sS, float* sCol, int tid) {
  for (int k = 0; k < NYY; ++k) {
    const float piv  = sS[SWZ(k, k)];
    const float pinv = 1.0f / piv;
    if (tid < NYY) {
      const int j = tid;
      sCol[j] = sS[SWZ(j, k)];
      if (j != k) sS[SWZ(k, j)] *= pinv;
    }
    __syncthreads();
    {
      const int i  = tid >> 2;
      const int jb = (tid & 3) * 16;
      if (i != k) {
        const float f = sCol[i];
#pragma unroll
        for (int jj = 0; jj < 16; ++jj) {
          const int j = jb + jj;
          if (j == k) sS[SWZ(i, k)] = -f * pinv;
          else        sS[SWZ(i, j)] -= f * sS[SWZ(k, j)];
        }
      } else if (k >= jb && k < jb + 16) {
        sS[SWZ(k, k)] = pinv;
      }
    }
    __syncthreads();
  }
}

// ---------------------------------------------------------------------------
// K1: Riccati recursion -> converged gain L_inf (+ transposed copy).
// Carries G_t = Pi_t @ W (128x64). Per iteration:
//   S = R + W^T G;  Sinv via gated Newton-Schulz (GJ fallback);
//   H = F G;  M = H^T W;  X = Sinv M;  G' = CWq - H X.
// All matmul-phase LDS reads vectorized as float4 with XOR component perm.
// Exit path always uses a full GJ inversion (exact final L).
// ---------------------------------------------------------------------------
__global__ __launch_bounds__(256, 1)
void lkf_gains(const float* __restrict__ F, const float* __restrict__ W,
               const float* __restrict__ Q, const float* __restrict__ R,
               const float* __restrict__ P0, float* __restrict__ Linf,
               float* __restrict__ LinfT, float* __restrict__ CWq,
               float* __restrict__ tmpA, float* __restrict__ tmpB)
{
  __shared__ __align__(16) float sG[NXX * NYY];   // 32 KB: G, later H
  __shared__ __align__(16) float sS[NYY * NYY];   // 16 KB: S -> Sinv/X scratch
  __shared__ __align__(16) float sM[NYY * NYY];   // 16 KB: T/M; aliased sCol/sRed
  __shared__ __align__(16) float sW[NXX * NYY];   // 32 KB: W resident
  __shared__ __align__(16) float sZ[NYY * NYY];   // 16 KB: persistent S^-1 (NS)
  __shared__ int sBad;
  float* sCol = sM;
  float* sRed = sM;
  const int tid = threadIdx.x;

  // ---------------- prologue ------------------------------------------------
  for (int idx = tid; idx < NXX * NYY; idx += 256)
    sW[SWZ(idx >> 6, idx & 63)] = W[idx];
  // tmpA = F^T W
  for (int idx = tid; idx < NXX * NYY; idx += 256) {
    const int k = idx >> 6, j = idx & 63;
    float acc = 0.f;
    for (int i = 0; i < NXX; ++i) acc += F[i * NXX + k] * W[i * NYY + j];
    tmpA[idx] = acc;
  }
  __syncthreads();
  // CWq = F (F^T W) + Q W
  for (int idx = tid; idx < NXX * NYY; idx += 256) {
    const int i = idx >> 6, j = idx & 63;
    float acc = 0.f;
    for (int k = 0; k < NXX; ++k) acc += F[i * NXX + k] * tmpA[k * NYY + j];
    for (int k = 0; k < NXX; ++k) acc += Q[i * NXX + k] * W[k * NYY + j];
    CWq[idx] = acc;
  }
  // tmpB = P0 @ F^T
  for (int idx = tid; idx < NXX * NXX; idx += 256) {
    const int i = idx >> 7, j = idx & 127;
    float acc = 0.f;
    for (int k = 0; k < NXX; ++k) acc += P0[i * NXX + k] * F[j * NXX + k];
    tmpB[idx] = acc;
  }
  __syncthreads();
  // tmpA = F @ tmpB + Q  (Pi_0)
  for (int idx = tid; idx < NXX * NXX; idx += 256) {
    const int i = idx >> 7, j = idx & 127;
    float acc = Q[idx];
    for (int k = 0; k < NXX; ++k) acc += F[i * NXX + k] * tmpB[k * NXX + j];
    tmpA[idx] = acc;
  }
  __syncthreads();
  // sG = Pi_0 @ W (swizzled)
  for (int idx = tid; idx < NXX * NYY; idx += 256) {
    const int i = idx >> 6, j = idx & 63;
    float acc = 0.f;
    for (int k = 0; k < NXX; ++k) acc += tmpA[i * NXX + k] * W[k * NYY + j];
    sG[SWZ(i, j)] = acc;
  }
  __syncthreads();
  // Ft for coalesced column access in (d)
  for (int idx = tid; idx < NXX * NXX; idx += 256)
    tmpB[idx] = F[(idx & 127) * NXX + (idx >> 7)];
  const float* Ft = tmpB;

  const int i16 = (tid >> 4) * 4;
  const int j16 = (tid & 15) * 4;
  const int i32 = (tid >> 3) * 4;
  const int j32 = (tid & 7) * 8;

  float cwq[4][8], rreg[4][4];
#pragma unroll
  for (int a = 0; a < 4; ++a)
#pragma unroll
    for (int b = 0; b < 8; ++b)
      cwq[a][b] = CWq[(i32 + a) * NYY + j32 + b];
#pragma unroll
  for (int a = 0; a < 4; ++a)
#pragma unroll
    for (int b = 0; b < 4; ++b)
      rreg[a][b] = R[(i16 + a) * NYY + j16 + b];

  float prevG[4][8], diff[4][8];
#pragma unroll
  for (int a = 0; a < 4; ++a)
#pragma unroll
    for (int b = 0; b < 8; ++b) { prevG[a][b] = 1e30f; diff[a][b] = 0.f; }
  int   cc = 0;
  bool  fin = false;
  bool  jumped = false;
  float prevDelta = 1e30f;
  __syncthreads();

  // ---------------- main recursion -----------------------------------------
  for (int t = 0; t < T_STEPS; ++t) {
    // (a) S = R + W^T G   (float4 LDS reads, identical arithmetic order)
    {
      float acc[4][4];
#pragma unroll
      for (int a = 0; a < 4; ++a)
#pragma unroll
        for (int b = 0; b < 4; ++b) acc[a][b] = 0.f;
      for (int kb = 0; kb < NXX; kb += 4) {
#pragma unroll
        for (int kk = 0; kk < 4; ++kk) {
          const int k = kb + kk;
          const float4 wv = ld4swz(sW, k, i16);
          const float4 gv = ld4swz(sG, k, j16);
          const float* wf = (const float*)&wv;
          const float* gf = (const float*)&gv;
#pragma unroll
          for (int a = 0; a < 4; ++a)
#pragma unroll
            for (int b = 0; b < 4; ++b)
              acc[a][b] += wf[a ^ kk] * gf[b ^ kk];
        }
      }
#pragma unroll
      for (int a = 0; a < 4; ++a)
#pragma unroll
        for (int b = 0; b < 4; ++b)
          sS[SWZ(i16 + a, j16 + b)] = rreg[a][b] + acc[a][b];
    }
    if (tid == 0) sBad = 0;
    __syncthreads();

    // exit path: exact GJ inverse, L_inf = G @ Sinv -> global, done.
    if (fin || t == T_STEPS - 1) {
      gj64(sS, sCol, tid);
      float acc[4][8];
#pragma unroll
      for (int a = 0; a < 4; ++a)
#pragma unroll
        for (int b = 0; b < 8; ++b) acc[a][b] = 0.f;
      for (int k = 0; k < NYY; ++k) {
        float g4[4], s8[8];
#pragma unroll
        for (int a = 0; a < 4; ++a) g4[a] = sG[SWZ(i32 + a, k)];
#pragma unroll
        for (int b = 0; b < 8; ++b) s8[b] = sS[SWZ(k, j32 + b)];
#pragma unroll
        for (int a = 0; a < 4; ++a)
#pragma unroll
          for (int b = 0; b < 8; ++b) acc[a][b] += g4[a] * s8[b];
      }
#pragma unroll
      for (int a = 0; a < 4; ++a)
#pragma unroll
        for (int b = 0; b < 8; ++b) {
          Linf[(i32 + a) * NYY + j32 + b]  = acc[a][b];
          LinfT[(j32 + b) * NXX + i32 + a] = acc[a][b];
        }
      break;
    }

    // (b) inversion: gated Newton-Schulz on persistent sZ, GJ fallback.
    bool gj = jumped || !(prevDelta <= 1e-2f);
    jumped = false;
    if (!gj) {
      const int nsteps = (prevDelta > 1e-4f) ? 2 : 1;
      for (int it = 0; it < nsteps; ++it) {
        // T = S @ Z -> sM   (S, Z numerically symmetric: read rows)
        float acc[4][4];
#pragma unroll
        for (int a = 0; a < 4; ++a)
#pragma unroll
          for (int b = 0; b < 4; ++b) acc[a][b] = 0.f;
        for (int kb = 0; kb < NYY; kb += 4) {
#pragma unroll
          for (int kk = 0; kk < 4; ++kk) {
            const int k = kb + kk;
            const float4 sv = ld4swz(sS, k, i16);
            const float4 zv = ld4swz(sZ, k, j16);
            const float* sf = (const float*)&sv;
            const float* zf = (const float*)&zv;
#pragma unroll
            for (int a = 0; a < 4; ++a)
#pragma unroll
              for (int b = 0; b < 4; ++b)
                acc[a][b] += sf[a ^ kk] * zf[b ^ kk];
          }
        }
        if (it == 0) {
          float loc = 0.f;
#pragma unroll
          for (int a = 0; a < 4; ++a)
#pragma unroll
            for (int b = 0; b < 4; ++b)
              loc = fmaxf(loc,
                          fabsf(acc[a][b] - ((i16 + a == j16 + b) ? 1.f : 0.f)));
          if (!(loc <= 0.06f)) sBad = 1;   // NaN-safe reject
        }
#pragma unroll
        for (int a = 0; a < 4; ++a) {
          float4 w; float* wf = (float*)&w;
#pragma unroll
          for (int b = 0; b < 4; ++b) wf[b ^ a] = acc[a][b];
          st4swz(sM, i16 + a, j16, w);
        }
        __syncthreads();
        if (it == 0 && sBad) { gj = true; break; }

        // Z = 2Z - Z @ T  (in place, read-all / barrier / write)
        float accu[4][4];
#pragma unroll
        for (int a = 0; a < 4; ++a)
#pragma unroll
          for (int b = 0; b < 4; ++b) accu[a][b] = 0.f;
        for (int kb = 0; kb < NYY; kb += 4) {
#pragma unroll
          for (int kk = 0; kk < 4; ++kk) {
            const int k = kb + kk;
            const float4 zv = ld4swz(sZ, k, i16);
            const float4 tv = ld4swz(sM, k, j16);
            const float* zf = (const float*)&zv;
            const float* tf = (const float*)&tv;
#pragma unroll
            for (int a = 0; a < 4; ++a)
#pragma unroll
              for (int b = 0; b < 4; ++b)
                accu[a][b] += zf[a ^ kk] * tf[b ^ kk];
          }
        }
        float4 zov[4];
#pragma unroll
        for (int a = 0; a < 4; ++a) zov[a] = ld4swz(sZ, i16 + a, j16);
        __syncthreads();
#pragma unroll
        for (int a = 0; a < 4; ++a) {
          float4 w; float* wf = (float*)&w;
          const float* zof = (const float*)&zov[a];
#pragma unroll
          for (int b = 0; b < 4; ++b)
            wf[b ^ a] = 2.f * zof[b ^ a] - accu[a][b];
          st4swz(sZ, i16 + a, j16, w);
        }
        __syncthreads();
      }
    }
    if (gj) {
      gj64(sS, sCol, tid);
      for (int idx = tid; idx < NYY * NYY; idx += 256) sZ[idx] = sS[idx];
      __syncthreads();
    }

    // (d) H = F @ G, overwrite sG
    {
      float acc[4][8];
#pragma unroll
      for (int a = 0; a < 4; ++a)
#pragma unroll
        for (int b = 0; b < 8; ++b) acc[a][b] = 0.f;
      for (int kb = 0; kb < NXX; kb += 4) {
#pragma unroll
        for (int kk = 0; kk < 4; ++kk) {
          const int k = kb + kk;
          float f4[4];
#pragma unroll
          for (int a = 0; a < 4; ++a) f4[a] = Ft[k * NXX + i32 + a];
          const float4 gv0 = ld4swz(sG, k, j32);
          const float4 gv1 = ld4swz(sG, k, j32 + 4);
          const float* gf0 = (const float*)&gv0;
          const float* gf1 = (const float*)&gv1;
#pragma unroll
          for (int a = 0; a < 4; ++a)
#pragma unroll
            for (int b = 0; b < 4; ++b) {
              acc[a][b]     += f4[a] * gf0[b ^ kk];
              acc[a][b + 4] += f4[a] * gf1[b ^ kk];
            }
        }
      }
      __syncthreads();
#pragma unroll
      for (int a = 0; a < 4; ++a)
#pragma unroll
        for (int b = 0; b < 8; ++b)
          sG[SWZ(i32 + a, j32 + b)] = acc[a][b];
    }
    __syncthreads();

    // (e) M = H^T W -> sM
    {
      float acc[4][4];
#pragma unroll
      for (int a = 0; a < 4; ++a)
#pragma unroll
        for (int b = 0; b < 4; ++b) acc[a][b] = 0.f;
      for (int kb = 0; kb < NXX; kb += 4) {
#pragma unroll
        for (int kk = 0; kk < 4; ++kk) {
          const int k = kb + kk;
          const float4 hv = ld4swz(sG, k, i16);
          const float4 wv = ld4swz(sW, k, j16);
          const float* hf = (const float*)&hv;
          const float* wf = (const float*)&wv;
#pragma unroll
          for (int a = 0; a < 4; ++a)
#pragma unroll
            for (int b = 0; b < 4; ++b)
              acc[a][b] += hf[a ^ kk] * wf[b ^ kk];
        }
      }
#pragma unroll
      for (int a = 0; a < 4; ++a)
#pragma unroll
        for (int b = 0; b < 4; ++b)
          sM[SWZ(i16 + a, j16 + b)] = acc[a][b];
    }
    __syncthreads();

    // (f) X = Z @ M -> sS
    {
      float acc[4][4];
#pragma unroll
      for (int a = 0; a < 4; ++a)
#pragma unroll
        for (int b = 0; b < 4; ++b) acc[a][b] = 0.f;
      for (int kb = 0; kb < NYY; kb += 4) {
#pragma unroll
        for (int kk = 0; kk < 4; ++kk) {
          const int k = kb + kk;
          const float4 zv = ld4swz(sZ, k, i16);   // Z symmetric
          const float4 mv = ld4swz(sM, k, j16);
          const float* zf = (const float*)&zv;
          const float* mf = (const float*)&mv;
#pragma unroll
          for (int a = 0; a < 4; ++a)
#pragma unroll
            for (int b = 0; b < 4; ++b)
              acc[a][b] += zf[a ^ kk] * mf[b ^ kk];
        }
      }
      __syncthreads();
#pragma unroll
      for (int a = 0; a < 4; ++a)
#pragma unroll
        for (int b = 0; b < 4; ++b)
          sS[SWZ(i16 + a, j16 + b)] = acc[a][b];
    }
    __syncthreads();

    // (g) G' = CWq - H @ X -> sG; delta + diff for Aitken
    float gdelta = 0.f;
    {
      float acc[4][8];
#pragma unroll
      for (int a = 0; a < 4; ++a)
#pragma unroll
        for (int b = 0; b < 8; ++b) acc[a][b] = 0.f;
      for (int kb = 0; kb < NYY; kb += 4) {
#pragma unroll
        for (int kk = 0; kk < 4; ++kk) {
          const int k = kb + kk;
          float h4[4];
#pragma unroll
          for (int a = 0; a < 4; ++a) h4[a] = sG[SWZ(i32 + a, k)];
          const float4 xv0 = ld4swz(sS, k, j32);
          const float4 xv1 = ld4swz(sS, k, j32 + 4);
          const float* xf0 = (const float*)&xv0;
          const float* xf1 = (const float*)&xv1;
#pragma unroll
          for (int a = 0; a < 4; ++a)
#pragma unroll
            for (int b = 0; b < 4; ++b) {
              acc[a][b]     += h4[a] * xf0[b ^ kk];
              acc[a][b + 4] += h4[a] * xf1[b ^ kk];
            }
        }
      }
      __syncthreads();
#pragma unroll
      for (int a = 0; a < 4; ++a)
#pragma unroll
        for (int b = 0; b < 8; ++b) {
          const float g = cwq[a][b] - acc[a][b];
          sG[SWZ(i32 + a, j32 + b)] = g;
          const float d = g - prevG[a][b];
          diff[a][b] = d;
          gdelta = fmaxf(gdelta, fabsf(d));
          prevG[a][b] = g;
        }
    }
    __syncthreads();
    sRed[tid] = gdelta;
    __syncthreads();
    if (tid < 64) {
      float m = fmaxf(fmaxf(sRed[tid], sRed[tid + 64]),
                      fmaxf(sRed[tid + 128], sRed[tid + 192]));
#pragma unroll
      for (int off = 32; off >= 1; off >>= 1)
        m = fmaxf(m, __shfl_down(m, off));
      if (tid == 0) sRed[0] = m;
    }
    __syncthreads();
    const float delta = sRed[0];
    const float r     = delta / prevDelta;
    prevDelta = delta;
    cc = (delta < 3e-5f) ? cc + 1 : 0;
    if (cc >= 2) fin = true;
    __syncthreads();

    // Aitken delta^2 jump (uniform condition; self-correcting afterwards)
    if (!fin && t >= 40 && ((t - 8) & 31) == 0 && r > 0.5f && r < 0.99f) {
      const float alpha = fminf(r / (1.0f - r), 25.0f);
#pragma unroll
      for (int a = 0; a < 4; ++a)
#pragma unroll
        for (int b = 0; b < 8; ++b) {
          const float g = prevG[a][b] + alpha * diff[a][b];
          sG[SWZ(i32 + a, j32 + b)] = g;
          prevG[a][b] = g;
        }
      jumped = true;   // Z stale after jump -> force GJ next iteration
      __syncthreads();
    }
  }
}

// ---------------------------------------------------------------------------
// K1b: fold L_inf into constant step matrices.
// ---------------------------------------------------------------------------
__global__ __launch_bounds__(64, 1)
void lkf_fuse(const float* __restrict__ F, const float* __restrict__ Wfu,
              const float* __restrict__ Wfd, const float* __restrict__ Wy,
              const float* __restrict__ bfx, const float* __restrict__ bfu,
              const float* __restrict__ bfd, const float* __restrict__ bfy,
              const float* __restrict__ Linf, float* __restrict__ Az,
              float* __restrict__ Buz, float* __restrict__ Bdz,
              float* __restrict__ cz)
{
  __shared__ float srow[NXX];
  __shared__ float fw[NYY];
  const int w = blockIdx.x, tid = threadIdx.x;

  for (int k = tid; k < NXX; k += 64) {
    float v;
    if (w < 128)      v = F[w * NXX + k];
    else if (w < 160) v = Wfu[(w - 128) * NXX + k];
    else if (w < 176) v = Wfd[(w - 160) * NXX + k];
    else              v = bfx[k] + bfu[k] + bfd[k];
    srow[k] = v;
  }
  __syncthreads();
  {
    const int m = tid;
    float acc = (w == 176) ? bfy[m] : 0.f;
    for (int k = 0; k < NXX; ++k) acc += srow[k] * Wy[k * NYY + m];
    fw[m] = acc;
  }
  __syncthreads();
  for (int j = tid; j < NXX; j += 64) {
    float s = 0.f;
    for (int m = 0; m < NYY; ++m) s += fw[m] * Linf[j * NYY + m];
    const float val = srow[j] - s;
    if (w < 128)      Az[w * NXX + j] = val;
    else if (w < 160) Buz[(w - 128) * NXX + j] = val;
    else if (w < 176) Bdz[(w - 160) * NXX + j] = val;
    else              cz[j] = val;
  }
}

// ---------------------------------------------------------------------------
// K1c: 128x128 matrix squaring (for A^64 via 6 repeated squarings).
// ---------------------------------------------------------------------------
__global__ __launch_bounds__(256, 1)
void mat_sq(const float* __restrict__ in, float* __restrict__ out)
{
  const int gid = blockIdx.x * 256 + threadIdx.x;  // grid 64 -> 16384 = 128*128
  const int i = gid >> 7, j = gid & 127;
  float acc = 0.f;
  for (int k = 0; k < NXX; ++k) acc += in[i * NXX + k] * in[k * NXX + j];
  out[gid] = acc;
}

// ---------------------------------------------------------------------------
// K2a: time-parallel chunk pass.  For chunk c of batch b compute
//   v_c = sum_{s=0..C-1} i_{cC+s} A^{C-1-s},   i_t = u_t Bu + d_t Bd + ym_t L^T + c
// via the recursion v <- v A + i_t with v_0 = 0 (same per-step form as the
// serial kernel).  8192 independent blocks -> whole-GPU compute-bound.
// 256 threads: thread (j, h) owns column j, k-half h (keeps VGPRs ~140).
// ---------------------------------------------------------------------------
__global__ __launch_bounds__(256, 2)
void lkf_chunk(const float* __restrict__ Yp, const float* __restrict__ Up,
               const float* __restrict__ Dp, const float* __restrict__ Az,
               const float* __restrict__ Buz, const float* __restrict__ Bdz,
               const float* __restrict__ cz, const float* __restrict__ LinfT,
               float* __restrict__ V)
{
  __shared__ __align__(16) float xs[2][NXX];
  __shared__ __align__(16) float ymb[2][NYY];
  __shared__ __align__(16) float ub[2][NUU];
  __shared__ __align__(16) float db[2][NDD];
  __shared__ float ps[NXX];

  const int tid = threadIdx.x;
  const int b   = blockIdx.x;       // batch
  const int c   = blockIdx.y;       // chunk
  const int j   = tid & 127;
  const int h   = tid >> 7;         // k-half

  float a[64], l[32], bu[16], bd[8];
#pragma unroll
  for (int k = 0; k < 64; ++k) a[k] = Az[(h * 64 + k) * NXX + j];
#pragma unroll
  for (int m = 0; m < 32; ++m) l[m] = LinfT[(h * 32 + m) * NXX + j];
#pragma unroll
  for (int k = 0; k < 16; ++k) bu[k] = Buz[(h * 16 + k) * NXX + j];
#pragma unroll
  for (int k = 0; k < 8; ++k)  bd[k] = Bdz[(h * 8 + k) * NXX + j];
  const float cj = (h == 0) ? cz[j] : 0.f;

  const int t0 = c * CCH;
  if (tid < 128) xs[0][tid] = 0.f;
  {
    const size_t tb = (size_t)t0 * BATCH + b;
    if (tid < 64)       ymb[0][tid]     = Yp[tb * NYY + tid];
    else if (tid < 96)  ub[0][tid - 64] = Up[tb * NUU + (tid - 64)];
    else if (tid < 112) db[0][tid - 96] = Dp[tb * NDD + (tid - 96)];
  }
  __syncthreads();

  for (int s = 0; s < CCH; ++s) {
    const int p = s & 1;

    float pf = 0.f;
    if (s < CCH - 1) {
      const size_t tb = (size_t)(t0 + s + 1) * BATCH + b;
      if (tid < 64)       pf = Yp[tb * NYY + tid];
      else if (tid < 96)  pf = Up[tb * NUU + (tid - 64)];
      else if (tid < 112) pf = Dp[tb * NDD + (tid - 96)];
    }

    float acc0 = cj, acc1 = 0.f, acc2 = 0.f, acc3 = 0.f;
    {
      const float4* x4 = (const float4*)(xs[p] + h * 64);
#pragma unroll
      for (int k4 = 0; k4 < 16; ++k4) {
        const float4 xv = x4[k4];
        acc0 += xv.x * a[4 * k4 + 0];
        acc1 += xv.y * a[4 * k4 + 1];
        acc2 += xv.z * a[4 * k4 + 2];
        acc3 += xv.w * a[4 * k4 + 3];
      }
      const float4* y4 = (const float4*)(ymb[p] + h * 32);
#pragma unroll
      for (int m4 = 0; m4 < 8; ++m4) {
        const float4 yv = y4[m4];
        acc0 += yv.x * l[4 * m4 + 0];
        acc1 += yv.y * l[4 * m4 + 1];
        acc2 += yv.z * l[4 * m4 + 2];
        acc3 += yv.w * l[4 * m4 + 3];
      }
      const float4* u4 = (const float4*)(ub[p] + h * 16);
#pragma unroll
      for (int k4 = 0; k4 < 4; ++k4) {
        const float4 uv = u4[k4];
        acc0 += uv.x * bu[4 * k4 + 0];
        acc1 += uv.y * bu[4 * k4 + 1];
        acc2 += uv.z * bu[4 * k4 + 2];
        acc3 += uv.w * bu[4 * k4 + 3];
      }
      const float4* d4 = (const float4*)(db[p] + h * 8);
#pragma unroll
      for (int k4 = 0; k4 < 2; ++k4) {
        const float4 dv = d4[k4];
        acc0 += dv.x * bd[4 * k4 + 0];
        acc1 += dv.y * bd[4 * k4 + 1];
        acc2 += dv.z * bd[4 * k4 + 2];
        acc3 += dv.w * bd[4 * k4 + 3];
      }
    }
    const float part = (acc0 + acc1) + (acc2 + acc3);
    if (h == 1) ps[j] = part;
    __syncthreads();
    if (h == 0) xs[1 - p][j] = part + ps[j];
    if (s < CCH - 1) {
      if (tid < 64)       ymb[1 - p][tid]     = pf;
      else if (tid < 96)  ub[1 - p][tid - 64] = pf;
      else if (tid < 112) db[1 - p][tid - 96] = pf;
    }
    __syncthreads();
  }

  if (tid < 128)
    V[((size_t)b * NCH + c) * NXX + tid] = xs[0][tid];   // CCH even -> xs[0]
}

// ---------------------------------------------------------------------------
// K2b: serial chunk combine:  x <- x A^64 + v_c,  c = 0..NCH-1; out = x.
// ---------------------------------------------------------------------------
__global__ __launch_bounds__(128, 1)
void lkf_comb(const float* __restrict__ A64, const float* __restrict__ V,
              const float* __restrict__ x0, float* __restrict__ out)
{
  __shared__ __align__(16) float xs[2][NXX];
  const int tid = threadIdx.x;
  const int b   = blockIdx.x;
  float a[NXX];
#pragma unroll
  for (int k = 0; k < NXX; ++k) a[k] = A64[k * NXX + tid];
  xs[0][tid] = x0[tid];
  __syncthreads();
  for (int c = 0; c < NCH; ++c) {
    const int p = c & 1;
    float acc0 = V[((size_t)b * NCH + c) * NXX + tid];
    float acc1 = 0.f, acc2 = 0.f, acc3 = 0.f;
    const float4* x4 = (const float4*)xs[p];
#pragma unroll
    for (int k4 = 0; k4 < NXX / 4; ++k4) {
      const float4 xv = x4[k4];
      acc0 += xv.x * a[4 * k4 + 0];
      acc1 += xv.y * a[4 * k4 + 1];
      acc2 += xv.z * a[4 * k4 + 2];
      acc3 += xv.w * a[4 * k4 + 3];
    }
    xs[1 - p][tid] = (acc0 + acc1) + (acc2 + acc3);
    __syncthreads();
  }
  out[(size_t)b * NXX + tid] = xs[0][tid];   // NCH even -> xs[0]
}

// ---------------------------------------------------------------------------
// K2 (fallback, unchanged): fully serial state recursion; used only when the
// workspace is too small for the chunk path.
// ---------------------------------------------------------------------------
__global__ __launch_bounds__(128, 1)
void lkf_state(const float* __restrict__ Yp, const float* __restrict__ Up,
               const float* __restrict__ Dp, const float* __restrict__ Az,
               const float* __restrict__ Buz, const float* __restrict__ Bdz,
               const float* __restrict__ cz, const float* __restrict__ LinfT,
               const float* __restrict__ x0, float* __restrict__ out)
{
  __shared__ __align__(16) float xs[2][NXX];
  __shared__ __align__(16) float ymb[2][NYY];
  __shared__ __align__(16) float ub[2][NUU];
  __shared__ __align__(16) float db[2][NDD];

  const int tid = threadIdx.x;
  const int b   = blockIdx.x;
  const int j   = tid;

  float a[NXX], l[NYY], bu[NUU], bd[NDD];
#pragma unroll
  for (int k = 0; k < NXX; ++k) a[k] = Az[k * NXX + j];
#pragma unroll
  for (int m = 0; m < NYY; ++m) l[m] = LinfT[m * NXX + j];
#pragma unroll
  for (int k = 0; k < NUU; ++k) bu[k] = Buz[k * NXX + j];
#pragma unroll
  for (int k = 0; k < NDD; ++k) bd[k] = Bdz[k * NXX + j];
  const float cj = cz[j];

  xs[0][tid] = x0[tid];
  if (tid < 64)       ymb[0][tid]     = Yp[(size_t)b * NYY + tid];
  else if (tid < 96)  ub[0][tid - 64] = Up[(size_t)b * NUU + (tid - 64)];
  else if (tid < 112) db[0][tid - 96] = Dp[(size_t)b * NDD + (tid - 96)];
  __syncthreads();

  for (int t = 0; t < T_STEPS; ++t) {
    const int p = t & 1;
    float pf = 0.f;
    if (t < T_STEPS - 1) {
      const size_t tb = (size_t)(t + 1) * BATCH + b;
      if (tid < 64)       pf = Yp[tb * NYY + tid];
      else if (tid < 96)  pf = Up[tb * NUU + (tid - 64)];
      else if (tid < 112) pf = Dp[tb * NDD + (tid - 96)];
    }

    float acc0 = cj, acc1 = 0.f, acc2 = 0.f, acc3 = 0.f;
    {
      const float4* x4 = (const float4*)xs[p];
#pragma unroll
      for (int k4 = 0; k4 < NXX / 4; ++k4) {
        const float4 xv = x4[k4];
        acc0 += xv.x * a[4 * k4 + 0];
        acc1 += xv.y * a[4 * k4 + 1];
        acc2 += xv.z * a[4 * k4 + 2];
        acc3 += xv.w * a[4 * k4 + 3];
      }
      const float4* y4 = (const float4*)ymb[p];
#pragma unroll
      for (int m4 = 0; m4 < NYY / 4; ++m4) {
        const float4 yv = y4[m4];
        acc0 += yv.x * l[4 * m4 + 0];
        acc1 += yv.y * l[4 * m4 + 1];
        acc2 += yv.z * l[4 * m4 + 2];
        acc3 += yv.w * l[4 * m4 + 3];
      }
      const float4* u4 = (const float4*)ub[p];
#pragma unroll
      for (int k4 = 0; k4 < NUU / 4; ++k4) {
        const float4 uv = u4[k4];
        acc0 += uv.x * bu[4 * k4 + 0];
        acc1 += uv.y * bu[4 * k4 + 1];
        acc2 += uv.z * bu[4 * k4 + 2];
        acc3 += uv.w * bu[4 * k4 + 3];
      }
      const float4* d4 = (const float4*)db[p];
#pragma unroll
      for (int k4 = 0; k4 < NDD / 4; ++k4) {
        const float4 dv = d4[k4];
        acc0 += dv.x * bd[4 * k4 + 0];
        acc1 += dv.y * bd[4 * k4 + 1];
        acc2 += dv.z * bd[4 * k4 + 2];
        acc3 += dv.w * bd[4 * k4 + 3];
      }
    }
    xs[1 - p][j] = (acc0 + acc1) + (acc2 + acc3);

    if (t < T_STEPS - 1) {
      if (tid < 64)       ymb[1 - p][tid]     = pf;
      else if (tid < 96)  ub[1 - p][tid - 64] = pf;
      else if (tid < 112) db[1 - p][tid - 96] = pf;
    }
    __syncthreads();
  }

  out[(size_t)b * NXX + j] = xs[0][j];
}

// ---------------------------------------------------------------------------
extern "C" void kernel_launch(void* const* d_in, const int* in_sizes, int n_in,
                              void* d_out, int out_size, void* d_ws,
                              size_t ws_size, hipStream_t stream) {
  const float* Yp  = (const float*)d_in[0];
  const float* Up  = (const float*)d_in[1];
  const float* Dp  = (const float*)d_in[2];
  const float* Wfx = (const float*)d_in[3];
  const float* bfx = (const float*)d_in[4];
  const float* Wfu = (const float*)d_in[5];
  const float* bfu = (const float*)d_in[6];
  const float* Wfd = (const float*)d_in[7];
  const float* bfd = (const float*)d_in[8];
  const float* Wfy = (const float*)d_in[9];
  const float* bfy = (const float*)d_in[10];
  const float* Q   = (const float*)d_in[11];
  const float* R   = (const float*)d_in[12];
  const float* P0  = (const float*)d_in[13];
  const float* x0  = (const float*)d_in[15];

  float* ws    = (float*)d_ws;
  float* Linf  = ws;                      // 128*64
  float* LinfT = Linf  + NXX * NYY;       // 64*128
  float* CWq   = LinfT + NYY * NXX;       // 128*64
  float* tmpA  = CWq   + NXX * NYY;       // 128*128
  float* tmpB  = tmpA  + NXX * NXX;       // 128*128
  float* Az    = tmpB  + NXX * NXX;       // 128*128
  float* Buz   = Az    + NXX * NXX;       // 32*128
  float* Bdz   = Buz   + NUU * NXX;       // 16*128
  float* cz    = Bdz   + NDD * NXX;       // 128
  float* pA    = cz    + NXX;             // 128*128 (A^2k ping)
  float* pB    = pA    + NXX * NXX;       // 128*128 (A^2k pong)
  float* V     = pB    + NXX * NXX;       // 256*32*128 = 4 MB

  const size_t needBytes =
      ((size_t)(V - ws) + (size_t)BATCH * NCH * NXX) * sizeof(float);

  lkf_gains<<<dim3(1), dim3(256), 0, stream>>>(Wfx, Wfy, Q, R, P0, Linf, LinfT,
                                               CWq, tmpA, tmpB);
  lkf_fuse<<<dim3(177), dim3(64), 0, stream>>>(Wfx, Wfu, Wfd, Wfy, bfx, bfu,
                                               bfd, bfy, Linf, Az, Buz, Bdz,
                                               cz);

  if (ws_size >= needBytes) {
    // A^64 by repeated squaring: Az->pA (A^2), ... , pA->pB (A^64)
    mat_sq<<<dim3(64), dim3(256), 0, stream>>>(Az, pA);
    mat_sq<<<dim3(64), dim3(256), 0, stream>>>(pA, pB);
    mat_sq<<<dim3(64), dim3(256), 0, stream>>>(pB, pA);
    mat_sq<<<dim3(64), dim3(256), 0, stream>>>(pA, pB);
    mat_sq<<<dim3(64), dim3(256), 0, stream>>>(pB, pA);
    mat_sq<<<dim3(64), dim3(256), 0, stream>>>(pA, pB);   // pB = A^64
    lkf_chunk<<<dim3(BATCH, NCH), dim3(256), 0, stream>>>(
        Yp, Up, Dp, Az, Buz, Bdz, cz, LinfT, V);
    lkf_comb<<<dim3(BATCH), dim3(128), 0, stream>>>(pB, V, x0, (float*)d_out);
  } else {
    lkf_state<<<dim3(BATCH), dim3(128), 0, stream>>>(
        Yp, Up, Dp, Az, Buz, Bdz, cz, LinfT, x0, (float*)d_out);
  }
}

// Round 2
// 4244.170 us; speedup vs baseline: 42.0585x; 42.0585x over previous
//
#include <hip/hip_runtime.h>

#define T_STEPS 2048
#define BATCH   256
#define NXX     128
#define NYY     64
#define NUU     32
#define NDD     16

#define CCH     64
#define NCH     (T_STEPS / CCH)   // 32 chunks

// XOR swizzle: conflict-free LDS for row- and column-pattern access.
#define SWZ(i, j) (((i) << 6) + ((j) ^ ((i) & 31)))

// ---------------------------------------------------------------------------
// K1: Riccati recursion -> converged gain L_inf (+ transposed copy).
// Carries G_t = Pi_t @ W (128x64):
//   S = R + W^T G;  H = F G;  G' = CWq - H (Sinv (H^T W))
// W LDS-resident (sW). Aitken delta^2 extrapolation every 32 steps (t>=40)
// using the measured geometric ratio r; self-correcting (iteration continues).
// (Round-0 verbatim: exact GJ inversion every iteration; NS variant broke
// convergence -> 2048 iters. Do not re-introduce stateful approximate
// inverses inside the convergence loop.)
// ---------------------------------------------------------------------------
__global__ __launch_bounds__(256, 1)
void lkf_gains(const float* __restrict__ F, const float* __restrict__ W,
               const float* __restrict__ Q, const float* __restrict__ R,
               const float* __restrict__ P0, float* __restrict__ Linf,
               float* __restrict__ LinfT, float* __restrict__ CWq,
               float* __restrict__ tmpA, float* __restrict__ tmpB)
{
  __shared__ float sG[NXX * NYY];   // 32 KB (swizzled): G, later H
  __shared__ float sS[NYY * NYY];   // 16 KB (swizzled): S -> Sinv -> X
  __shared__ float sM[NYY * NYY];   // 16 KB (swizzled): M; aliased sCol/sRed
  __shared__ float sW[NXX * NYY];   // 32 KB (swizzled): W resident
  float* sCol = sM;
  float* sRed = sM;
  const int tid = threadIdx.x;

  // ---------------- prologue ------------------------------------------------
  // sW = W (swizzled)
  for (int idx = tid; idx < NXX * NYY; idx += 256)
    sW[SWZ(idx >> 6, idx & 63)] = W[idx];
  // tmpA = F^T W
  for (int idx = tid; idx < NXX * NYY; idx += 256) {
    const int k = idx >> 6, j = idx & 63;
    float acc = 0.f;
    for (int i = 0; i < NXX; ++i) acc += F[i * NXX + k] * W[i * NYY + j];
    tmpA[idx] = acc;
  }
  __syncthreads();
  // CWq = F (F^T W) + Q W
  for (int idx = tid; idx < NXX * NYY; idx += 256) {
    const int i = idx >> 6, j = idx & 63;
    float acc = 0.f;
    for (int k = 0; k < NXX; ++k) acc += F[i * NXX + k] * tmpA[k * NYY + j];
    for (int k = 0; k < NXX; ++k) acc += Q[i * NXX + k] * W[k * NYY + j];
    CWq[idx] = acc;
  }
  // tmpB = P0 @ F^T
  for (int idx = tid; idx < NXX * NXX; idx += 256) {
    const int i = idx >> 7, j = idx & 127;
    float acc = 0.f;
    for (int k = 0; k < NXX; ++k) acc += P0[i * NXX + k] * F[j * NXX + k];
    tmpB[idx] = acc;
  }
  __syncthreads();
  // tmpA = F @ tmpB + Q  (Pi_0)
  for (int idx = tid; idx < NXX * NXX; idx += 256) {
    const int i = idx >> 7, j = idx & 127;
    float acc = Q[idx];
    for (int k = 0; k < NXX; ++k) acc += F[i * NXX + k] * tmpB[k * NXX + j];
    tmpA[idx] = acc;
  }
  __syncthreads();
  // sG = Pi_0 @ W (swizzled)
  for (int idx = tid; idx < NXX * NYY; idx += 256) {
    const int i = idx >> 6, j = idx & 63;
    float acc = 0.f;
    for (int k = 0; k < NXX; ++k) acc += tmpA[i * NXX + k] * W[k * NYY + j];
    sG[SWZ(i, j)] = acc;
  }
  __syncthreads();
  // Ft for coalesced column access in (d)
  for (int idx = tid; idx < NXX * NXX; idx += 256)
    tmpB[idx] = F[(idx & 127) * NXX + (idx >> 7)];
  const float* Ft = tmpB;

  const int i16 = (tid >> 4) * 4;
  const int j16 = (tid & 15) * 4;
  const int i32 = (tid >> 3) * 4;
  const int j32 = (tid & 7) * 8;

  float cwq[4][8], rreg[4][4];
#pragma unroll
  for (int a = 0; a < 4; ++a)
#pragma unroll
    for (int b = 0; b < 8; ++b)
      cwq[a][b] = CWq[(i32 + a) * NYY + j32 + b];
#pragma unroll
  for (int a = 0; a < 4; ++a)
#pragma unroll
    for (int b = 0; b < 4; ++b)
      rreg[a][b] = R[(i16 + a) * NYY + j16 + b];

  float prevG[4][8], diff[4][8];
#pragma unroll
  for (int a = 0; a < 4; ++a)
#pragma unroll
    for (int b = 0; b < 8; ++b) { prevG[a][b] = 1e30f; diff[a][b] = 0.f; }
  int   cc = 0;
  bool  fin = false;
  float prevDelta = 1e30f;
  __syncthreads();

  // ---------------- main recursion -----------------------------------------
  for (int t = 0; t < T_STEPS; ++t) {
    // (a) S = R + W^T G
    {
      float acc[4][4];
#pragma unroll
      for (int a = 0; a < 4; ++a)
#pragma unroll
        for (int b = 0; b < 4; ++b) acc[a][b] = 0.f;
      for (int k = 0; k < NXX; ++k) {
        float w4[4], g4[4];
#pragma unroll
        for (int a = 0; a < 4; ++a) w4[a] = sW[SWZ(k, i16 + a)];
#pragma unroll
        for (int b = 0; b < 4; ++b) g4[b] = sG[SWZ(k, j16 + b)];
#pragma unroll
        for (int a = 0; a < 4; ++a)
#pragma unroll
          for (int b = 0; b < 4; ++b) acc[a][b] += w4[a] * g4[b];
      }
#pragma unroll
      for (int a = 0; a < 4; ++a)
#pragma unroll
        for (int b = 0; b < 4; ++b)
          sS[SWZ(i16 + a, j16 + b)] = rreg[a][b] + acc[a][b];
    }
    __syncthreads();

    // (b) Gauss-Jordan inversion of sS
    for (int k = 0; k < NYY; ++k) {
      const float piv  = sS[SWZ(k, k)];
      const float pinv = 1.0f / piv;
      if (tid < NYY) {
        const int j = tid;
        sCol[j] = sS[SWZ(j, k)];
        if (j != k) sS[SWZ(k, j)] *= pinv;
      }
      __syncthreads();
      {
        const int i  = tid >> 2;
        const int jb = (tid & 3) * 16;
        if (i != k) {
          const float f = sCol[i];
#pragma unroll
          for (int jj = 0; jj < 16; ++jj) {
            const int j = jb + jj;
            if (j == k) sS[SWZ(i, k)] = -f * pinv;
            else        sS[SWZ(i, j)] -= f * sS[SWZ(k, j)];
          }
        } else if (k >= jb && k < jb + 16) {
          sS[SWZ(k, k)] = pinv;
        }
      }
      __syncthreads();
    } // sS = Sinv

    // exit path: L_inf = G @ Sinv -> global (row-major + transposed), done.
    if (fin || t == T_STEPS - 1) {
      float acc[4][8];
#pragma unroll
      for (int a = 0; a < 4; ++a)
#pragma unroll
        for (int b = 0; b < 8; ++b) acc[a][b] = 0.f;
      for (int k = 0; k < NYY; ++k) {
        float g4[4], s8[8];
#pragma unroll
        for (int a = 0; a < 4; ++a) g4[a] = sG[SWZ(i32 + a, k)];
#pragma unroll
        for (int b = 0; b < 8; ++b) s8[b] = sS[SWZ(k, j32 + b)];
#pragma unroll
        for (int a = 0; a < 4; ++a)
#pragma unroll
          for (int b = 0; b < 8; ++b) acc[a][b] += g4[a] * s8[b];
      }
#pragma unroll
      for (int a = 0; a < 4; ++a)
#pragma unroll
        for (int b = 0; b < 8; ++b) {
          Linf[(i32 + a) * NYY + j32 + b]  = acc[a][b];
          LinfT[(j32 + b) * NXX + i32 + a] = acc[a][b];
        }
      break;
    }

    // (d) H = F @ G, overwrite sG
    {
      float acc[4][8];
#pragma unroll
      for (int a = 0; a < 4; ++a)
#pragma unroll
        for (int b = 0; b < 8; ++b) acc[a][b] = 0.f;
      for (int k = 0; k < NXX; ++k) {
        float f4[4], g8[8];
#pragma unroll
        for (int a = 0; a < 4; ++a) f4[a] = Ft[k * NXX + i32 + a];
#pragma unroll
        for (int b = 0; b < 8; ++b) g8[b] = sG[SWZ(k, j32 + b)];
#pragma unroll
        for (int a = 0; a < 4; ++a)
#pragma unroll
          for (int b = 0; b < 8; ++b) acc[a][b] += f4[a] * g8[b];
      }
      __syncthreads();
#pragma unroll
      for (int a = 0; a < 4; ++a)
#pragma unroll
        for (int b = 0; b < 8; ++b)
          sG[SWZ(i32 + a, j32 + b)] = acc[a][b];
    }
    __syncthreads();

    // (e) M = H^T W -> sM
    {
      float acc[4][4];
#pragma unroll
      for (int a = 0; a < 4; ++a)
#pragma unroll
        for (int b = 0; b < 4; ++b) acc[a][b] = 0.f;
      for (int k = 0; k < NXX; ++k) {
        float h4[4], w4[4];
#pragma unroll
        for (int a = 0; a < 4; ++a) h4[a] = sG[SWZ(k, i16 + a)];
#pragma unroll
        for (int b = 0; b < 4; ++b) w4[b] = sW[SWZ(k, j16 + b)];
#pragma unroll
        for (int a = 0; a < 4; ++a)
#pragma unroll
          for (int b = 0; b < 4; ++b) acc[a][b] += h4[a] * w4[b];
      }
#pragma unroll
      for (int a = 0; a < 4; ++a)
#pragma unroll
        for (int b = 0; b < 4; ++b)
          sM[SWZ(i16 + a, j16 + b)] = acc[a][b];
    }
    __syncthreads();

    // (f) X = Sinv @ M -> sS
    {
      float acc[4][4];
#pragma unroll
      for (int a = 0; a < 4; ++a)
#pragma unroll
        for (int b = 0; b < 4; ++b) acc[a][b] = 0.f;
      for (int k = 0; k < NYY; ++k) {
        float s4[4], m4[4];
#pragma unroll
        for (int a = 0; a < 4; ++a) s4[a] = sS[SWZ(i16 + a, k)];
#pragma unroll
        for (int b = 0; b < 4; ++b) m4[b] = sM[SWZ(k, j16 + b)];
#pragma unroll
        for (int a = 0; a < 4; ++a)
#pragma unroll
          for (int b = 0; b < 4; ++b) acc[a][b] += s4[a] * m4[b];
      }
      __syncthreads();
#pragma unroll
      for (int a = 0; a < 4; ++a)
#pragma unroll
        for (int b = 0; b < 4; ++b)
          sS[SWZ(i16 + a, j16 + b)] = acc[a][b];
    }
    __syncthreads();

    // (g) G' = CWq - H @ X -> sG; delta + diff for Aitken
    float gdelta = 0.f;
    {
      float acc[4][8];
#pragma unroll
      for (int a = 0; a < 4; ++a)
#pragma unroll
        for (int b = 0; b < 8; ++b) acc[a][b] = 0.f;
      for (int k = 0; k < NYY; ++k) {
        float h4[4], x8[8];
#pragma unroll
        for (int a = 0; a < 4; ++a) h4[a] = sG[SWZ(i32 + a, k)];
#pragma unroll
        for (int b = 0; b < 8; ++b) x8[b] = sS[SWZ(k, j32 + b)];
#pragma unroll
        for (int a = 0; a < 4; ++a)
#pragma unroll
          for (int b = 0; b < 8; ++b) acc[a][b] += h4[a] * x8[b];
      }
      __syncthreads();
#pragma unroll
      for (int a = 0; a < 4; ++a)
#pragma unroll
        for (int b = 0; b < 8; ++b) {
          const float g = cwq[a][b] - acc[a][b];
          sG[SWZ(i32 + a, j32 + b)] = g;
          const float d = g - prevG[a][b];
          diff[a][b] = d;
          gdelta = fmaxf(gdelta, fabsf(d));
          prevG[a][b] = g;
        }
    }
    __syncthreads();
    sRed[tid] = gdelta;
    __syncthreads();
    if (tid < 64) {
      float m = fmaxf(fmaxf(sRed[tid], sRed[tid + 64]),
                      fmaxf(sRed[tid + 128], sRed[tid + 192]));
#pragma unroll
      for (int off = 32; off >= 1; off >>= 1)
        m = fmaxf(m, __shfl_down(m, off));
      if (tid == 0) sRed[0] = m;
    }
    __syncthreads();
    const float delta = sRed[0];
    const float r     = delta / prevDelta;
    prevDelta = delta;
    cc = (delta < 3e-5f) ? cc + 1 : 0;
    if (cc >= 2) fin = true;
    __syncthreads();

    // Aitken delta^2 jump (uniform condition; self-correcting afterwards)
    if (!fin && t >= 40 && ((t - 8) & 31) == 0 && r > 0.5f && r < 0.99f) {
      const float alpha = fminf(r / (1.0f - r), 25.0f);
#pragma unroll
      for (int a = 0; a < 4; ++a)
#pragma unroll
        for (int b = 0; b < 8; ++b) {
          const float g = prevG[a][b] + alpha * diff[a][b];
          sG[SWZ(i32 + a, j32 + b)] = g;
          prevG[a][b] = g;
        }
      __syncthreads();
    }
  }
}

// ---------------------------------------------------------------------------
// K1b: fold L_inf into constant step matrices.
//   A  = F   - (F  @Wy) L^T   [128x128]
//   Bu = Wfu - (Wfu@Wy) L^T   [ 32x128]
//   Bd = Wfd - (Wfd@Wy) L^T   [ 16x128]
//   c  = bsum - (bsum@Wy + bfy) L^T   [128]
// ---------------------------------------------------------------------------
__global__ __launch_bounds__(64, 1)
void lkf_fuse(const float* __restrict__ F, const float* __restrict__ Wfu,
              const float* __restrict__ Wfd, const float* __restrict__ Wy,
              const float* __restrict__ bfx, const float* __restrict__ bfu,
              const float* __restrict__ bfd, const float* __restrict__ bfy,
              const float* __restrict__ Linf, float* __restrict__ Az,
              float* __restrict__ Buz, float* __restrict__ Bdz,
              float* __restrict__ cz)
{
  __shared__ float srow[NXX];
  __shared__ float fw[NYY];
  const int w = blockIdx.x, tid = threadIdx.x;

  for (int k = tid; k < NXX; k += 64) {
    float v;
    if (w < 128)      v = F[w * NXX + k];
    else if (w < 160) v = Wfu[(w - 128) * NXX + k];
    else if (w < 176) v = Wfd[(w - 160) * NXX + k];
    else              v = bfx[k] + bfu[k] + bfd[k];
    srow[k] = v;
  }
  __syncthreads();
  {
    const int m = tid;
    float acc = (w == 176) ? bfy[m] : 0.f;
    for (int k = 0; k < NXX; ++k) acc += srow[k] * Wy[k * NYY + m];
    fw[m] = acc;
  }
  __syncthreads();
  for (int j = tid; j < NXX; j += 64) {
    float s = 0.f;
    for (int m = 0; m < NYY; ++m) s += fw[m] * Linf[j * NYY + m];
    const float val = srow[j] - s;
    if (w < 128)      Az[w * NXX + j] = val;
    else if (w < 160) Buz[(w - 128) * NXX + j] = val;
    else if (w < 176) Bdz[(w - 160) * NXX + j] = val;
    else              cz[j] = val;
  }
}

// ---------------------------------------------------------------------------
// K1c: 128x128 matrix squaring (for A^64 via 6 repeated squarings).
// ---------------------------------------------------------------------------
__global__ __launch_bounds__(256, 1)
void mat_sq(const float* __restrict__ in, float* __restrict__ out)
{
  const int gid = blockIdx.x * 256 + threadIdx.x;  // grid 64 -> 16384 = 128*128
  const int i = gid >> 7, j = gid & 127;
  float acc = 0.f;
  for (int k = 0; k < NXX; ++k) acc += in[i * NXX + k] * in[k * NXX + j];
  out[gid] = acc;
}

// ---------------------------------------------------------------------------
// K2a: time-parallel chunk pass.  For chunk c of batch b compute
//   v_c = sum_{s=0..C-1} i_{cC+s} A^{C-1-s},   i_t = u_t Bu + d_t Bd + ym_t L^T + c
// via the recursion v <- v A + i_t with v_0 = 0 (same per-step form as the
// serial kernel).  8192 independent blocks -> whole-GPU compute-bound.
// 256 threads: thread (j, h) owns column j, k-half h.
// ---------------------------------------------------------------------------
__global__ __launch_bounds__(256, 2)
void lkf_chunk(const float* __restrict__ Yp, const float* __restrict__ Up,
               const float* __restrict__ Dp, const float* __restrict__ Az,
               const float* __restrict__ Buz, const float* __restrict__ Bdz,
               const float* __restrict__ cz, const float* __restrict__ LinfT,
               float* __restrict__ V)
{
  __shared__ __align__(16) float xs[2][NXX];
  __shared__ __align__(16) float ymb[2][NYY];
  __shared__ __align__(16) float ub[2][NUU];
  __shared__ __align__(16) float db[2][NDD];
  __shared__ float ps[NXX];

  const int tid = threadIdx.x;
  const int b   = blockIdx.x;       // batch
  const int c   = blockIdx.y;       // chunk
  const int j   = tid & 127;
  const int h   = tid >> 7;         // k-half

  float a[64], l[32], bu[16], bd[8];
#pragma unroll
  for (int k = 0; k < 64; ++k) a[k] = Az[(h * 64 + k) * NXX + j];
#pragma unroll
  for (int m = 0; m < 32; ++m) l[m] = LinfT[(h * 32 + m) * NXX + j];
#pragma unroll
  for (int k = 0; k < 16; ++k) bu[k] = Buz[(h * 16 + k) * NXX + j];
#pragma unroll
  for (int k = 0; k < 8; ++k)  bd[k] = Bdz[(h * 8 + k) * NXX + j];
  const float cj = (h == 0) ? cz[j] : 0.f;

  const int t0 = c * CCH;
  if (tid < 128) xs[0][tid] = 0.f;
  {
    const size_t tb = (size_t)t0 * BATCH + b;
    if (tid < 64)       ymb[0][tid]     = Yp[tb * NYY + tid];
    else if (tid < 96)  ub[0][tid - 64] = Up[tb * NUU + (tid - 64)];
    else if (tid < 112) db[0][tid - 96] = Dp[tb * NDD + (tid - 96)];
  }
  __syncthreads();

  for (int s = 0; s < CCH; ++s) {
    const int p = s & 1;

    float pf = 0.f;
    if (s < CCH - 1) {
      const size_t tb = (size_t)(t0 + s + 1) * BATCH + b;
      if (tid < 64)       pf = Yp[tb * NYY + tid];
      else if (tid < 96)  pf = Up[tb * NUU + (tid - 64)];
      else if (tid < 112) pf = Dp[tb * NDD + (tid - 96)];
    }

    float acc0 = cj, acc1 = 0.f, acc2 = 0.f, acc3 = 0.f;
    {
      const float4* x4 = (const float4*)(xs[p] + h * 64);
#pragma unroll
      for (int k4 = 0; k4 < 16; ++k4) {
        const float4 xv = x4[k4];
        acc0 += xv.x * a[4 * k4 + 0];
        acc1 += xv.y * a[4 * k4 + 1];
        acc2 += xv.z * a[4 * k4 + 2];
        acc3 += xv.w * a[4 * k4 + 3];
      }
      const float4* y4 = (const float4*)(ymb[p] + h * 32);
#pragma unroll
      for (int m4 = 0; m4 < 8; ++m4) {
        const float4 yv = y4[m4];
        acc0 += yv.x * l[4 * m4 + 0];
        acc1 += yv.y * l[4 * m4 + 1];
        acc2 += yv.z * l[4 * m4 + 2];
        acc3 += yv.w * l[4 * m4 + 3];
      }
      const float4* u4 = (const float4*)(ub[p] + h * 16);
#pragma unroll
      for (int k4 = 0; k4 < 4; ++k4) {
        const float4 uv = u4[k4];
        acc0 += uv.x * bu[4 * k4 + 0];
        acc1 += uv.y * bu[4 * k4 + 1];
        acc2 += uv.z * bu[4 * k4 + 2];
        acc3 += uv.w * bu[4 * k4 + 3];
      }
      const float4* d4 = (const float4*)(db[p] + h * 8);
#pragma unroll
      for (int k4 = 0; k4 < 2; ++k4) {
        const float4 dv = d4[k4];
        acc0 += dv.x * bd[4 * k4 + 0];
        acc1 += dv.y * bd[4 * k4 + 1];
        acc2 += dv.z * bd[4 * k4 + 2];
        acc3 += dv.w * bd[4 * k4 + 3];
      }
    }
    const float part = (acc0 + acc1) + (acc2 + acc3);
    if (h == 1) ps[j] = part;
    __syncthreads();
    if (h == 0) xs[1 - p][j] = part + ps[j];
    if (s < CCH - 1) {
      if (tid < 64)       ymb[1 - p][tid]     = pf;
      else if (tid < 96)  ub[1 - p][tid - 64] = pf;
      else if (tid < 112) db[1 - p][tid - 96] = pf;
    }
    __syncthreads();
  }

  if (tid < 128)
    V[((size_t)b * NCH + c) * NXX + tid] = xs[0][tid];   // CCH even -> xs[0]
}

// ---------------------------------------------------------------------------
// K2b: serial chunk combine:  x <- x A^64 + v_c,  c = 0..NCH-1; out = x.
// ---------------------------------------------------------------------------
__global__ __launch_bounds__(128, 1)
void lkf_comb(const float* __restrict__ A64, const float* __restrict__ V,
              const float* __restrict__ x0, float* __restrict__ out)
{
  __shared__ __align__(16) float xs[2][NXX];
  const int tid = threadIdx.x;
  const int b   = blockIdx.x;
  float a[NXX];
#pragma unroll
  for (int k = 0; k < NXX; ++k) a[k] = A64[k * NXX + tid];
  xs[0][tid] = x0[tid];
  __syncthreads();
  for (int c = 0; c < NCH; ++c) {
    const int p = c & 1;
    float acc0 = V[((size_t)b * NCH + c) * NXX + tid];
    float acc1 = 0.f, acc2 = 0.f, acc3 = 0.f;
    const float4* x4 = (const float4*)xs[p];
#pragma unroll
    for (int k4 = 0; k4 < NXX / 4; ++k4) {
      const float4 xv = x4[k4];
      acc0 += xv.x * a[4 * k4 + 0];
      acc1 += xv.y * a[4 * k4 + 1];
      acc2 += xv.z * a[4 * k4 + 2];
      acc3 += xv.w * a[4 * k4 + 3];
    }
    xs[1 - p][tid] = (acc0 + acc1) + (acc2 + acc3);
    __syncthreads();
  }
  out[(size_t)b * NXX + tid] = xs[0][tid];   // NCH even -> xs[0]
}

// ---------------------------------------------------------------------------
// K2 (fallback): fully serial state recursion; used only when the workspace
// is too small for the chunk path.
// ---------------------------------------------------------------------------
__global__ __launch_bounds__(128, 1)
void lkf_state(const float* __restrict__ Yp, const float* __restrict__ Up,
               const float* __restrict__ Dp, const float* __restrict__ Az,
               const float* __restrict__ Buz, const float* __restrict__ Bdz,
               const float* __restrict__ cz, const float* __restrict__ LinfT,
               const float* __restrict__ x0, float* __restrict__ out)
{
  __shared__ __align__(16) float xs[2][NXX];
  __shared__ __align__(16) float ymb[2][NYY];
  __shared__ __align__(16) float ub[2][NUU];
  __shared__ __align__(16) float db[2][NDD];

  const int tid = threadIdx.x;
  const int b   = blockIdx.x;
  const int j   = tid;

  float a[NXX], l[NYY], bu[NUU], bd[NDD];
#pragma unroll
  for (int k = 0; k < NXX; ++k) a[k] = Az[k * NXX + j];
#pragma unroll
  for (int m = 0; m < NYY; ++m) l[m] = LinfT[m * NXX + j];
#pragma unroll
  for (int k = 0; k < NUU; ++k) bu[k] = Buz[k * NXX + j];
#pragma unroll
  for (int k = 0; k < NDD; ++k) bd[k] = Bdz[k * NXX + j];
  const float cj = cz[j];

  xs[0][tid] = x0[tid];
  if (tid < 64)       ymb[0][tid]     = Yp[(size_t)b * NYY + tid];
  else if (tid < 96)  ub[0][tid - 64] = Up[(size_t)b * NUU + (tid - 64)];
  else if (tid < 112) db[0][tid - 96] = Dp[(size_t)b * NDD + (tid - 96)];
  __syncthreads();

  for (int t = 0; t < T_STEPS; ++t) {
    const int p = t & 1;
    float pf = 0.f;
    if (t < T_STEPS - 1) {
      const size_t tb = (size_t)(t + 1) * BATCH + b;
      if (tid < 64)       pf = Yp[tb * NYY + tid];
      else if (tid < 96)  pf = Up[tb * NUU + (tid - 64)];
      else if (tid < 112) pf = Dp[tb * NDD + (tid - 96)];
    }

    float acc0 = cj, acc1 = 0.f, acc2 = 0.f, acc3 = 0.f;
    {
      const float4* x4 = (const float4*)xs[p];
#pragma unroll
      for (int k4 = 0; k4 < NXX / 4; ++k4) {
        const float4 xv = x4[k4];
        acc0 += xv.x * a[4 * k4 + 0];
        acc1 += xv.y * a[4 * k4 + 1];
        acc2 += xv.z * a[4 * k4 + 2];
        acc3 += xv.w * a[4 * k4 + 3];
      }
      const float4* y4 = (const float4*)ymb[p];
#pragma unroll
      for (int m4 = 0; m4 < NYY / 4; ++m4) {
        const float4 yv = y4[m4];
        acc0 += yv.x * l[4 * m4 + 0];
        acc1 += yv.y * l[4 * m4 + 1];
        acc2 += yv.z * l[4 * m4 + 2];
        acc3 += yv.w * l[4 * m4 + 3];
      }
      const float4* u4 = (const float4*)ub[p];
#pragma unroll
      for (int k4 = 0; k4 < NUU / 4; ++k4) {
        const float4 uv = u4[k4];
        acc0 += uv.x * bu[4 * k4 + 0];
        acc1 += uv.y * bu[4 * k4 + 1];
        acc2 += uv.z * bu[4 * k4 + 2];
        acc3 += uv.w * bu[4 * k4 + 3];
      }
      const float4* d4 = (const float4*)db[p];
#pragma unroll
      for (int k4 = 0; k4 < NDD / 4; ++k4) {
        const float4 dv = d4[k4];
        acc0 += dv.x * bd[4 * k4 + 0];
        acc1 += dv.y * bd[4 * k4 + 1];
        acc2 += dv.z * bd[4 * k4 + 2];
        acc3 += dv.w * bd[4 * k4 + 3];
      }
    }
    xs[1 - p][j] = (acc0 + acc1) + (acc2 + acc3);

    if (t < T_STEPS - 1) {
      if (tid < 64)       ymb[1 - p][tid]     = pf;
      else if (tid < 96)  ub[1 - p][tid - 64] = pf;
      else if (tid < 112) db[1 - p][tid - 96] = pf;
    }
    __syncthreads();
  }

  out[(size_t)b * NXX + j] = xs[0][j];
}

// ---------------------------------------------------------------------------
extern "C" void kernel_launch(void* const* d_in, const int* in_sizes, int n_in,
                              void* d_out, int out_size, void* d_ws,
                              size_t ws_size, hipStream_t stream) {
  const float* Yp  = (const float*)d_in[0];
  const float* Up  = (const float*)d_in[1];
  const float* Dp  = (const float*)d_in[2];
  const float* Wfx = (const float*)d_in[3];
  const float* bfx = (const float*)d_in[4];
  const float* Wfu = (const float*)d_in[5];
  const float* bfu = (const float*)d_in[6];
  const float* Wfd = (const float*)d_in[7];
  const float* bfd = (const float*)d_in[8];
  const float* Wfy = (const float*)d_in[9];
  const float* bfy = (const float*)d_in[10];
  const float* Q   = (const float*)d_in[11];
  const float* R   = (const float*)d_in[12];
  const float* P0  = (const float*)d_in[13];
  const float* x0  = (const float*)d_in[15];

  float* ws    = (float*)d_ws;
  float* Linf  = ws;                      // 128*64
  float* LinfT = Linf  + NXX * NYY;       // 64*128
  float* CWq   = LinfT + NYY * NXX;       // 128*64
  float* tmpA  = CWq   + NXX * NYY;       // 128*128
  float* tmpB  = tmpA  + NXX * NXX;       // 128*128
  float* Az    = tmpB  + NXX * NXX;       // 128*128
  float* Buz   = Az    + NXX * NXX;       // 32*128
  float* Bdz   = Buz   + NUU * NXX;       // 16*128
  float* cz    = Bdz   + NDD * NXX;       // 128
  float* pA    = cz    + NXX;             // 128*128 (A^2k ping)
  float* pB    = pA    + NXX * NXX;       // 128*128 (A^2k pong)
  float* V     = pB    + NXX * NXX;       // 256*32*128 = 4 MB

  const size_t needBytes =
      ((size_t)(V - ws) + (size_t)BATCH * NCH * NXX) * sizeof(float);

  lkf_gains<<<dim3(1), dim3(256), 0, stream>>>(Wfx, Wfy, Q, R, P0, Linf, LinfT,
                                               CWq, tmpA, tmpB);
  lkf_fuse<<<dim3(177), dim3(64), 0, stream>>>(Wfx, Wfu, Wfd, Wfy, bfx, bfu,
                                               bfd, bfy, Linf, Az, Buz, Bdz,
                                               cz);

  if (ws_size >= needBytes) {
    // A^64 by repeated squaring: Az->pA (A^2), ... , pA->pB (A^64)
    mat_sq<<<dim3(64), dim3(256), 0, stream>>>(Az, pA);
    mat_sq<<<dim3(64), dim3(256), 0, stream>>>(pA, pB);
    mat_sq<<<dim3(64), dim3(256), 0, stream>>>(pB, pA);
    mat_sq<<<dim3(64), dim3(256), 0, stream>>>(pA, pB);
    mat_sq<<<dim3(64), dim3(256), 0, stream>>>(pB, pA);
    mat_sq<<<dim3(64), dim3(256), 0, stream>>>(pA, pB);   // pB = A^64
    lkf_chunk<<<dim3(BATCH, NCH), dim3(256), 0, stream>>>(
        Yp, Up, Dp, Az, Buz, Bdz, cz, LinfT, V);
    lkf_comb<<<dim3(BATCH), dim3(128), 0, stream>>>(pB, V, x0, (float*)d_out);
  } else {
    lkf_state<<<dim3(BATCH), dim3(128), 0, stream>>>(
        Yp, Up, Dp, Az, Buz, Bdz, cz, LinfT, x0, (float*)d_out);
  }
}

// Round 3
// 2825.595 us; speedup vs baseline: 63.1737x; 1.5020x over previous
//
#include <hip/hip_runtime.h>

#define T_STEPS 2048
#define BATCH   256
#define NXX     128
#define NYY     64
#define NUU     32
#define NDD     16

#define CCH     64
#define NCH     (T_STEPS / CCH)   // 32 chunks

// XOR swizzle: conflict-free LDS for row- and column-pattern access.
#define SWZ(i, j) (((i) << 6) + ((j) ^ ((i) & 31)))

// For row r, aligned col-group cg (cg%4==0): elements [r][cg..cg+3] live in
// ONE contiguous aligned float4 at (r<<6) + (cg ^ (r&28)), with element
// (cg+b) at component (b ^ (r&3)).  All perms compile-time when r = k
// (kk-unrolled) or r = base+a with base 4-aligned.
__device__ __forceinline__ float4 ld4swz(const float* s, int row, int cg) {
  return *(const float4*)(s + (row << 6) + (cg ^ (row & 28)));
}
__device__ __forceinline__ void st4swz(float* s, int row, int cg, const float4& v) {
  *(float4*)(s + (row << 6) + (cg ^ (row & 28))) = v;
}

// ---------------------------------------------------------------------------
// K1: Riccati recursion -> converged gain L_inf (+ transposed copy).
// Same algorithm as the round-0 kernel (exact GJ inversion every iteration,
// Aitken every 32 steps; do NOT re-introduce stateful approximate inverses).
// This version only changes the LDS access width: float4 swizzled loads in
// the matmul phases and a uniform-update float4 Gauss-Jordan.
// ---------------------------------------------------------------------------
__global__ __launch_bounds__(256, 1)
void lkf_gains(const float* __restrict__ F, const float* __restrict__ W,
               const float* __restrict__ Q, const float* __restrict__ R,
               const float* __restrict__ P0, float* __restrict__ Linf,
               float* __restrict__ LinfT, float* __restrict__ CWq,
               float* __restrict__ tmpA, float* __restrict__ tmpB)
{
  __shared__ __align__(16) float sG[NXX * NYY];   // 32 KB (swizzled): G, later H
  __shared__ __align__(16) float sS[NYY * NYY];   // 16 KB (swizzled): S -> Sinv -> X
  __shared__ __align__(16) float sM[NYY * NYY];   // 16 KB (swizzled): M; aliased sCol/sRed
  __shared__ __align__(16) float sW[NXX * NYY];   // 32 KB (swizzled): W resident
  float* sCol = sM;
  float* sRed = sM;
  const int tid = threadIdx.x;

  // ---------------- prologue ------------------------------------------------
  for (int idx = tid; idx < NXX * NYY; idx += 256)
    sW[SWZ(idx >> 6, idx & 63)] = W[idx];
  // tmpA = F^T W
  for (int idx = tid; idx < NXX * NYY; idx += 256) {
    const int k = idx >> 6, j = idx & 63;
    float acc = 0.f;
    for (int i = 0; i < NXX; ++i) acc += F[i * NXX + k] * W[i * NYY + j];
    tmpA[idx] = acc;
  }
  __syncthreads();
  // CWq = F (F^T W) + Q W
  for (int idx = tid; idx < NXX * NYY; idx += 256) {
    const int i = idx >> 6, j = idx & 63;
    float acc = 0.f;
    for (int k = 0; k < NXX; ++k) acc += F[i * NXX + k] * tmpA[k * NYY + j];
    for (int k = 0; k < NXX; ++k) acc += Q[i * NXX + k] * W[k * NYY + j];
    CWq[idx] = acc;
  }
  // tmpB = P0 @ F^T
  for (int idx = tid; idx < NXX * NXX; idx += 256) {
    const int i = idx >> 7, j = idx & 127;
    float acc = 0.f;
    for (int k = 0; k < NXX; ++k) acc += P0[i * NXX + k] * F[j * NXX + k];
    tmpB[idx] = acc;
  }
  __syncthreads();
  // tmpA = F @ tmpB + Q  (Pi_0)
  for (int idx = tid; idx < NXX * NXX; idx += 256) {
    const int i = idx >> 7, j = idx & 127;
    float acc = Q[idx];
    for (int k = 0; k < NXX; ++k) acc += F[i * NXX + k] * tmpB[k * NXX + j];
    tmpA[idx] = acc;
  }
  __syncthreads();
  // sG = Pi_0 @ W (swizzled)
  for (int idx = tid; idx < NXX * NYY; idx += 256) {
    const int i = idx >> 6, j = idx & 63;
    float acc = 0.f;
    for (int k = 0; k < NXX; ++k) acc += tmpA[i * NXX + k] * W[k * NYY + j];
    sG[SWZ(i, j)] = acc;
  }
  __syncthreads();
  // Ft for coalesced column access in (d)
  for (int idx = tid; idx < NXX * NXX; idx += 256)
    tmpB[idx] = F[(idx & 127) * NXX + (idx >> 7)];
  const float* Ft = tmpB;

  const int i16 = (tid >> 4) * 4;
  const int j16 = (tid & 15) * 4;
  const int i32 = (tid >> 3) * 4;
  const int j32 = (tid & 7) * 8;

  float cwq[4][8], rreg[4][4];
#pragma unroll
  for (int a = 0; a < 4; ++a)
#pragma unroll
    for (int b = 0; b < 8; ++b)
      cwq[a][b] = CWq[(i32 + a) * NYY + j32 + b];
#pragma unroll
  for (int a = 0; a < 4; ++a)
#pragma unroll
    for (int b = 0; b < 4; ++b)
      rreg[a][b] = R[(i16 + a) * NYY + j16 + b];

  float prevG[4][8], diff[4][8];
#pragma unroll
  for (int a = 0; a < 4; ++a)
#pragma unroll
    for (int b = 0; b < 8; ++b) { prevG[a][b] = 1e30f; diff[a][b] = 0.f; }
  int   cc = 0;
  bool  fin = false;
  float prevDelta = 1e30f;
  __syncthreads();

  // ---------------- main recursion -----------------------------------------
  for (int t = 0; t < T_STEPS; ++t) {
    // (a) S = R + W^T G   (float4 swizzled reads; same FMA set as scalar)
    {
      float acc[4][4];
#pragma unroll
      for (int a = 0; a < 4; ++a)
#pragma unroll
        for (int b = 0; b < 4; ++b) acc[a][b] = 0.f;
      for (int kb = 0; kb < NXX; kb += 4) {
#pragma unroll
        for (int kk = 0; kk < 4; ++kk) {
          const int k = kb + kk;
          const float4 wv = ld4swz(sW, k, i16);
          const float4 gv = ld4swz(sG, k, j16);
          const float* wf = (const float*)&wv;
          const float* gf = (const float*)&gv;
#pragma unroll
          for (int a = 0; a < 4; ++a)
#pragma unroll
            for (int b = 0; b < 4; ++b)
              acc[a][b] += wf[a ^ kk] * gf[b ^ kk];
        }
      }
#pragma unroll
      for (int a = 0; a < 4; ++a) {
        float4 w; float* wf = (float*)&w;
#pragma unroll
        for (int b = 0; b < 4; ++b) wf[b ^ a] = rreg[a][b] + acc[a][b];
        st4swz(sS, i16 + a, j16, w);
      }
    }
    __syncthreads();

    // (b) Gauss-Jordan inversion of sS (uniform rank-1 update, float4 rows).
    // Prep (wave 0, lockstep-safe): save col k, zero it, scale row k with
    // S[k][k]=pinv.  Then uniform update S[i][:] -= c[i]*row_k for i != k
    // covers the k-column automatically (0 - c[i]*pinv).
    for (int kb = 0; kb < NYY; kb += 4) {
#pragma unroll
      for (int kk = 0; kk < 4; ++kk) {
        const int k = kb + kk;
        if (tid < NYY) {
          const int j = tid;
          const float piv  = sS[SWZ(k, k)];   // wave-0 lockstep read
          const float pinv = 1.0f / piv;
          const float cv   = sS[SWZ(j, k)];
          sCol[j] = cv;
          if (j != k) {
            sS[SWZ(k, j)] *= pinv;
            sS[SWZ(j, k)] = 0.f;
          } else {
            sS[SWZ(k, k)] = pinv;
          }
        }
        __syncthreads();
        {
          const float4 rk = ld4swz(sS, k, j16);            // row k (scaled)
          const float4 cf = *(const float4*)(sCol + i16);  // c for 4 rows
          const float* rkf = (const float*)&rk;
          const float* cff = (const float*)&cf;
#pragma unroll
          for (int a = 0; a < 4; ++a) {
            if (i16 + a != k) {
              float4 ri = ld4swz(sS, i16 + a, j16);
              float* rif = (float*)&ri;
              const float f = cff[a];
#pragma unroll
              for (int b = 0; b < 4; ++b)
                rif[b ^ a] -= f * rkf[b ^ kk];
              st4swz(sS, i16 + a, j16, ri);
            }
          }
        }
        __syncthreads();
      }
    } // sS = Sinv

    // exit path: L_inf = G @ Sinv -> global (row-major + transposed), done.
    if (fin || t == T_STEPS - 1) {
      float acc[4][8];
#pragma unroll
      for (int a = 0; a < 4; ++a)
#pragma unroll
        for (int b = 0; b < 8; ++b) acc[a][b] = 0.f;
      for (int k = 0; k < NYY; ++k) {
        float g4[4], s8[8];
#pragma unroll
        for (int a = 0; a < 4; ++a) g4[a] = sG[SWZ(i32 + a, k)];
#pragma unroll
        for (int b = 0; b < 8; ++b) s8[b] = sS[SWZ(k, j32 + b)];
#pragma unroll
        for (int a = 0; a < 4; ++a)
#pragma unroll
          for (int b = 0; b < 8; ++b) acc[a][b] += g4[a] * s8[b];
      }
#pragma unroll
      for (int a = 0; a < 4; ++a)
#pragma unroll
        for (int b = 0; b < 8; ++b) {
          Linf[(i32 + a) * NYY + j32 + b]  = acc[a][b];
          LinfT[(j32 + b) * NXX + i32 + a] = acc[a][b];
        }
      break;
    }

    // (d) H = F @ G, overwrite sG  (Ft rows as global float4)
    {
      float acc[4][8];
#pragma unroll
      for (int a = 0; a < 4; ++a)
#pragma unroll
        for (int b = 0; b < 8; ++b) acc[a][b] = 0.f;
      for (int kb = 0; kb < NXX; kb += 4) {
#pragma unroll
        for (int kk = 0; kk < 4; ++kk) {
          const int k = kb + kk;
          const float4 fv  = *(const float4*)(Ft + k * NXX + i32);
          const float4 gv0 = ld4swz(sG, k, j32);
          const float4 gv1 = ld4swz(sG, k, j32 + 4);
          const float* ff  = (const float*)&fv;
          const float* gf0 = (const float*)&gv0;
          const float* gf1 = (const float*)&gv1;
#pragma unroll
          for (int a = 0; a < 4; ++a)
#pragma unroll
            for (int b = 0; b < 4; ++b) {
              acc[a][b]     += ff[a] * gf0[b ^ kk];
              acc[a][b + 4] += ff[a] * gf1[b ^ kk];
            }
        }
      }
      __syncthreads();
#pragma unroll
      for (int a = 0; a < 4; ++a) {
        float4 w0, w1; float* wf0 = (float*)&w0; float* wf1 = (float*)&w1;
#pragma unroll
        for (int b = 0; b < 4; ++b) {
          wf0[b ^ a] = acc[a][b];
          wf1[b ^ a] = acc[a][b + 4];
        }
        st4swz(sG, i32 + a, j32, w0);
        st4swz(sG, i32 + a, j32 + 4, w1);
      }
    }
    __syncthreads();

    // (e) M = H^T W -> sM
    {
      float acc[4][4];
#pragma unroll
      for (int a = 0; a < 4; ++a)
#pragma unroll
        for (int b = 0; b < 4; ++b) acc[a][b] = 0.f;
      for (int kb = 0; kb < NXX; kb += 4) {
#pragma unroll
        for (int kk = 0; kk < 4; ++kk) {
          const int k = kb + kk;
          const float4 hv = ld4swz(sG, k, i16);
          const float4 wv = ld4swz(sW, k, j16);
          const float* hf = (const float*)&hv;
          const float* wf = (const float*)&wv;
#pragma unroll
          for (int a = 0; a < 4; ++a)
#pragma unroll
            for (int b = 0; b < 4; ++b)
              acc[a][b] += hf[a ^ kk] * wf[b ^ kk];
        }
      }
#pragma unroll
      for (int a = 0; a < 4; ++a) {
        float4 w; float* wf = (float*)&w;
#pragma unroll
        for (int b = 0; b < 4; ++b) wf[b ^ a] = acc[a][b];
        st4swz(sM, i16 + a, j16, w);
      }
    }
    __syncthreads();

    // (f) X = Sinv @ M -> sS (row-reads of Sinv, no symmetry assumption)
    {
      float acc[4][4];
#pragma unroll
      for (int a = 0; a < 4; ++a)
#pragma unroll
        for (int b = 0; b < 4; ++b) acc[a][b] = 0.f;
      for (int kb = 0; kb < NYY; kb += 4) {
        float4 sv[4];
#pragma unroll
        for (int a = 0; a < 4; ++a) sv[a] = ld4swz(sS, i16 + a, kb);
#pragma unroll
        for (int kk = 0; kk < 4; ++kk) {
          const float4 mv = ld4swz(sM, kb + kk, j16);
          const float* mf = (const float*)&mv;
#pragma unroll
          for (int a = 0; a < 4; ++a) {
            const float s = ((const float*)&sv[a])[kk ^ a];
#pragma unroll
            for (int b = 0; b < 4; ++b)
              acc[a][b] += s * mf[b ^ kk];
          }
        }
      }
      __syncthreads();
#pragma unroll
      for (int a = 0; a < 4; ++a) {
        float4 w; float* wf = (float*)&w;
#pragma unroll
        for (int b = 0; b < 4; ++b) wf[b ^ a] = acc[a][b];
        st4swz(sS, i16 + a, j16, w);
      }
    }
    __syncthreads();

    // (g) G' = CWq - H @ X -> sG; delta + diff for Aitken
    float gdelta = 0.f;
    {
      float acc[4][8];
#pragma unroll
      for (int a = 0; a < 4; ++a)
#pragma unroll
        for (int b = 0; b < 8; ++b) acc[a][b] = 0.f;
      for (int kb = 0; kb < NYY; kb += 4) {
        float4 hv[4];
#pragma unroll
        for (int a = 0; a < 4; ++a) hv[a] = ld4swz(sG, i32 + a, kb);
#pragma unroll
        for (int kk = 0; kk < 4; ++kk) {
          const float4 xv0 = ld4swz(sS, kb + kk, j32);
          const float4 xv1 = ld4swz(sS, kb + kk, j32 + 4);
          const float* xf0 = (const float*)&xv0;
          const float* xf1 = (const float*)&xv1;
#pragma unroll
          for (int a = 0; a < 4; ++a) {
            const float h = ((const float*)&hv[a])[kk ^ a];
#pragma unroll
            for (int b = 0; b < 4; ++b) {
              acc[a][b]     += h * xf0[b ^ kk];
              acc[a][b + 4] += h * xf1[b ^ kk];
            }
          }
        }
      }
      __syncthreads();
#pragma unroll
      for (int a = 0; a < 4; ++a) {
        float4 w0, w1; float* wf0 = (float*)&w0; float* wf1 = (float*)&w1;
#pragma unroll
        for (int b = 0; b < 4; ++b) {
          const float g0 = cwq[a][b]     - acc[a][b];
          const float g1 = cwq[a][b + 4] - acc[a][b + 4];
          wf0[b ^ a] = g0;
          wf1[b ^ a] = g1;
          const float d0 = g0 - prevG[a][b];
          const float d1 = g1 - prevG[a][b + 4];
          diff[a][b] = d0; diff[a][b + 4] = d1;
          gdelta = fmaxf(gdelta, fmaxf(fabsf(d0), fabsf(d1)));
          prevG[a][b] = g0; prevG[a][b + 4] = g1;
        }
        st4swz(sG, i32 + a, j32, w0);
        st4swz(sG, i32 + a, j32 + 4, w1);
      }
    }
    __syncthreads();
    sRed[tid] = gdelta;
    __syncthreads();
    if (tid < 64) {
      float m = fmaxf(fmaxf(sRed[tid], sRed[tid + 64]),
                      fmaxf(sRed[tid + 128], sRed[tid + 192]));
#pragma unroll
      for (int off = 32; off >= 1; off >>= 1)
        m = fmaxf(m, __shfl_down(m, off));
      if (tid == 0) sRed[0] = m;
    }
    __syncthreads();
    const float delta = sRed[0];
    const float r     = delta / prevDelta;
    prevDelta = delta;
    cc = (delta < 3e-5f) ? cc + 1 : 0;
    if (cc >= 2) fin = true;
    __syncthreads();

    // Aitken delta^2 jump (uniform condition; self-correcting afterwards)
    if (!fin && t >= 40 && ((t - 8) & 31) == 0 && r > 0.5f && r < 0.99f) {
      const float alpha = fminf(r / (1.0f - r), 25.0f);
#pragma unroll
      for (int a = 0; a < 4; ++a)
#pragma unroll
        for (int b = 0; b < 8; ++b) {
          const float g = prevG[a][b] + alpha * diff[a][b];
          sG[SWZ(i32 + a, j32 + b)] = g;
          prevG[a][b] = g;
        }
      __syncthreads();
    }
  }
}

// ---------------------------------------------------------------------------
// K1b: fold L_inf into constant step matrices.
// ---------------------------------------------------------------------------
__global__ __launch_bounds__(64, 1)
void lkf_fuse(const float* __restrict__ F, const float* __restrict__ Wfu,
              const float* __restrict__ Wfd, const float* __restrict__ Wy,
              const float* __restrict__ bfx, const float* __restrict__ bfu,
              const float* __restrict__ bfd, const float* __restrict__ bfy,
              const float* __restrict__ Linf, float* __restrict__ Az,
              float* __restrict__ Buz, float* __restrict__ Bdz,
              float* __restrict__ cz)
{
  __shared__ float srow[NXX];
  __shared__ float fw[NYY];
  const int w = blockIdx.x, tid = threadIdx.x;

  for (int k = tid; k < NXX; k += 64) {
    float v;
    if (w < 128)      v = F[w * NXX + k];
    else if (w < 160) v = Wfu[(w - 128) * NXX + k];
    else if (w < 176) v = Wfd[(w - 160) * NXX + k];
    else              v = bfx[k] + bfu[k] + bfd[k];
    srow[k] = v;
  }
  __syncthreads();
  {
    const int m = tid;
    float acc = (w == 176) ? bfy[m] : 0.f;
    for (int k = 0; k < NXX; ++k) acc += srow[k] * Wy[k * NYY + m];
    fw[m] = acc;
  }
  __syncthreads();
  for (int j = tid; j < NXX; j += 64) {
    float s = 0.f;
    for (int m = 0; m < NYY; ++m) s += fw[m] * Linf[j * NYY + m];
    const float val = srow[j] - s;
    if (w < 128)      Az[w * NXX + j] = val;
    else if (w < 160) Buz[(w - 128) * NXX + j] = val;
    else if (w < 176) Bdz[(w - 160) * NXX + j] = val;
    else              cz[j] = val;
  }
}

// ---------------------------------------------------------------------------
// K1c: 128x128 matrix squaring (for A^64 via 6 repeated squarings).
// ---------------------------------------------------------------------------
__global__ __launch_bounds__(256, 1)
void mat_sq(const float* __restrict__ in, float* __restrict__ out)
{
  const int gid = blockIdx.x * 256 + threadIdx.x;  // grid 64 -> 16384 = 128*128
  const int i = gid >> 7, j = gid & 127;
  float acc = 0.f;
  for (int k = 0; k < NXX; ++k) acc += in[i * NXX + k] * in[k * NXX + j];
  out[gid] = acc;
}

// ---------------------------------------------------------------------------
// K2a: time-parallel chunk pass.  For chunk c of batch b compute
//   v_c = sum_{s=0..C-1} i_{cC+s} A^{C-1-s},   i_t = u_t Bu + d_t Bd + ym_t L^T + c
// via the recursion v <- v A + i_t with v_0 = 0.  8192 independent blocks.
// ---------------------------------------------------------------------------
__global__ __launch_bounds__(256, 2)
void lkf_chunk(const float* __restrict__ Yp, const float* __restrict__ Up,
               const float* __restrict__ Dp, const float* __restrict__ Az,
               const float* __restrict__ Buz, const float* __restrict__ Bdz,
               const float* __restrict__ cz, const float* __restrict__ LinfT,
               float* __restrict__ V)
{
  __shared__ __align__(16) float xs[2][NXX];
  __shared__ __align__(16) float ymb[2][NYY];
  __shared__ __align__(16) float ub[2][NUU];
  __shared__ __align__(16) float db[2][NDD];
  __shared__ float ps[NXX];

  const int tid = threadIdx.x;
  const int b   = blockIdx.x;       // batch
  const int c   = blockIdx.y;       // chunk
  const int j   = tid & 127;
  const int h   = tid >> 7;         // k-half

  float a[64], l[32], bu[16], bd[8];
#pragma unroll
  for (int k = 0; k < 64; ++k) a[k] = Az[(h * 64 + k) * NXX + j];
#pragma unroll
  for (int m = 0; m < 32; ++m) l[m] = LinfT[(h * 32 + m) * NXX + j];
#pragma unroll
  for (int k = 0; k < 16; ++k) bu[k] = Buz[(h * 16 + k) * NXX + j];
#pragma unroll
  for (int k = 0; k < 8; ++k)  bd[k] = Bdz[(h * 8 + k) * NXX + j];
  const float cj = (h == 0) ? cz[j] : 0.f;

  const int t0 = c * CCH;
  if (tid < 128) xs[0][tid] = 0.f;
  {
    const size_t tb = (size_t)t0 * BATCH + b;
    if (tid < 64)       ymb[0][tid]     = Yp[tb * NYY + tid];
    else if (tid < 96)  ub[0][tid - 64] = Up[tb * NUU + (tid - 64)];
    else if (tid < 112) db[0][tid - 96] = Dp[tb * NDD + (tid - 96)];
  }
  __syncthreads();

  for (int s = 0; s < CCH; ++s) {
    const int p = s & 1;

    float pf = 0.f;
    if (s < CCH - 1) {
      const size_t tb = (size_t)(t0 + s + 1) * BATCH + b;
      if (tid < 64)       pf = Yp[tb * NYY + tid];
      else if (tid < 96)  pf = Up[tb * NUU + (tid - 64)];
      else if (tid < 112) pf = Dp[tb * NDD + (tid - 96)];
    }

    float acc0 = cj, acc1 = 0.f, acc2 = 0.f, acc3 = 0.f;
    {
      const float4* x4 = (const float4*)(xs[p] + h * 64);
#pragma unroll
      for (int k4 = 0; k4 < 16; ++k4) {
        const float4 xv = x4[k4];
        acc0 += xv.x * a[4 * k4 + 0];
        acc1 += xv.y * a[4 * k4 + 1];
        acc2 += xv.z * a[4 * k4 + 2];
        acc3 += xv.w * a[4 * k4 + 3];
      }
      const float4* y4 = (const float4*)(ymb[p] + h * 32);
#pragma unroll
      for (int m4 = 0; m4 < 8; ++m4) {
        const float4 yv = y4[m4];
        acc0 += yv.x * l[4 * m4 + 0];
        acc1 += yv.y * l[4 * m4 + 1];
        acc2 += yv.z * l[4 * m4 + 2];
        acc3 += yv.w * l[4 * m4 + 3];
      }
      const float4* u4 = (const float4*)(ub[p] + h * 16);
#pragma unroll
      for (int k4 = 0; k4 < 4; ++k4) {
        const float4 uv = u4[k4];
        acc0 += uv.x * bu[4 * k4 + 0];
        acc1 += uv.y * bu[4 * k4 + 1];
        acc2 += uv.z * bu[4 * k4 + 2];
        acc3 += uv.w * bu[4 * k4 + 3];
      }
      const float4* d4 = (const float4*)(db[p] + h * 8);
#pragma unroll
      for (int k4 = 0; k4 < 2; ++k4) {
        const float4 dv = d4[k4];
        acc0 += dv.x * bd[4 * k4 + 0];
        acc1 += dv.y * bd[4 * k4 + 1];
        acc2 += dv.z * bd[4 * k4 + 2];
        acc3 += dv.w * bd[4 * k4 + 3];
      }
    }
    const float part = (acc0 + acc1) + (acc2 + acc3);
    if (h == 1) ps[j] = part;
    __syncthreads();
    if (h == 0) xs[1 - p][j] = part + ps[j];
    if (s < CCH - 1) {
      if (tid < 64)       ymb[1 - p][tid]     = pf;
      else if (tid < 96)  ub[1 - p][tid - 64] = pf;
      else if (tid < 112) db[1 - p][tid - 96] = pf;
    }
    __syncthreads();
  }

  if (tid < 128)
    V[((size_t)b * NCH + c) * NXX + tid] = xs[0][tid];   // CCH even -> xs[0]
}

// ---------------------------------------------------------------------------
// K2b: serial chunk combine:  x <- x A^64 + v_c,  c = 0..NCH-1; out = x.
// ---------------------------------------------------------------------------
__global__ __launch_bounds__(128, 1)
void lkf_comb(const float* __restrict__ A64, const float* __restrict__ V,
              const float* __restrict__ x0, float* __restrict__ out)
{
  __shared__ __align__(16) float xs[2][NXX];
  const int tid = threadIdx.x;
  const int b   = blockIdx.x;
  float a[NXX];
#pragma unroll
  for (int k = 0; k < NXX; ++k) a[k] = A64[k * NXX + tid];
  xs[0][tid] = x0[tid];
  __syncthreads();
  for (int c = 0; c < NCH; ++c) {
    const int p = c & 1;
    float acc0 = V[((size_t)b * NCH + c) * NXX + tid];
    float acc1 = 0.f, acc2 = 0.f, acc3 = 0.f;
    const float4* x4 = (const float4*)xs[p];
#pragma unroll
    for (int k4 = 0; k4 < NXX / 4; ++k4) {
      const float4 xv = x4[k4];
      acc0 += xv.x * a[4 * k4 + 0];
      acc1 += xv.y * a[4 * k4 + 1];
      acc2 += xv.z * a[4 * k4 + 2];
      acc3 += xv.w * a[4 * k4 + 3];
    }
    xs[1 - p][tid] = (acc0 + acc1) + (acc2 + acc3);
    __syncthreads();
  }
  out[(size_t)b * NXX + tid] = xs[0][tid];   // NCH even -> xs[0]
}

// ---------------------------------------------------------------------------
// K2 (fallback): fully serial state recursion; used only when the workspace
// is too small for the chunk path.
// ---------------------------------------------------------------------------
__global__ __launch_bounds__(128, 1)
void lkf_state(const float* __restrict__ Yp, const float* __restrict__ Up,
               const float* __restrict__ Dp, const float* __restrict__ Az,
               const float* __restrict__ Buz, const float* __restrict__ Bdz,
               const float* __restrict__ cz, const float* __restrict__ LinfT,
               const float* __restrict__ x0, float* __restrict__ out)
{
  __shared__ __align__(16) float xs[2][NXX];
  __shared__ __align__(16) float ymb[2][NYY];
  __shared__ __align__(16) float ub[2][NUU];
  __shared__ __align__(16) float db[2][NDD];

  const int tid = threadIdx.x;
  const int b   = blockIdx.x;
  const int j   = tid;

  float a[NXX], l[NYY], bu[NUU], bd[NDD];
#pragma unroll
  for (int k = 0; k < NXX; ++k) a[k] = Az[k * NXX + j];
#pragma unroll
  for (int m = 0; m < NYY; ++m) l[m] = LinfT[m * NXX + j];
#pragma unroll
  for (int k = 0; k < NUU; ++k) bu[k] = Buz[k * NXX + j];
#pragma unroll
  for (int k = 0; k < NDD; ++k) bd[k] = Bdz[k * NXX + j];
  const float cj = cz[j];

  xs[0][tid] = x0[tid];
  if (tid < 64)       ymb[0][tid]     = Yp[(size_t)b * NYY + tid];
  else if (tid < 96)  ub[0][tid - 64] = Up[(size_t)b * NUU + (tid - 64)];
  else if (tid < 112) db[0][tid - 96] = Dp[(size_t)b * NDD + (tid - 96)];
  __syncthreads();

  for (int t = 0; t < T_STEPS; ++t) {
    const int p = t & 1;
    float pf = 0.f;
    if (t < T_STEPS - 1) {
      const size_t tb = (size_t)(t + 1) * BATCH + b;
      if (tid < 64)       pf = Yp[tb * NYY + tid];
      else if (tid < 96)  pf = Up[tb * NUU + (tid - 64)];
      else if (tid < 112) pf = Dp[tb * NDD + (tid - 96)];
    }

    float acc0 = cj, acc1 = 0.f, acc2 = 0.f, acc3 = 0.f;
    {
      const float4* x4 = (const float4*)xs[p];
#pragma unroll
      for (int k4 = 0; k4 < NXX / 4; ++k4) {
        const float4 xv = x4[k4];
        acc0 += xv.x * a[4 * k4 + 0];
        acc1 += xv.y * a[4 * k4 + 1];
        acc2 += xv.z * a[4 * k4 + 2];
        acc3 += xv.w * a[4 * k4 + 3];
      }
      const float4* y4 = (const float4*)ymb[p];
#pragma unroll
      for (int m4 = 0; m4 < NYY / 4; ++m4) {
        const float4 yv = y4[m4];
        acc0 += yv.x * l[4 * m4 + 0];
        acc1 += yv.y * l[4 * m4 + 1];
        acc2 += yv.z * l[4 * m4 + 2];
        acc3 += yv.w * l[4 * m4 + 3];
      }
      const float4* u4 = (const float4*)ub[p];
#pragma unroll
      for (int k4 = 0; k4 < NUU / 4; ++k4) {
        const float4 uv = u4[k4];
        acc0 += uv.x * bu[4 * k4 + 0];
        acc1 += uv.y * bu[4 * k4 + 1];
        acc2 += uv.z * bu[4 * k4 + 2];
        acc3 += uv.w * bu[4 * k4 + 3];
      }
      const float4* d4 = (const float4*)db[p];
#pragma unroll
      for (int k4 = 0; k4 < NDD / 4; ++k4) {
        const float4 dv = d4[k4];
        acc0 += dv.x * bd[4 * k4 + 0];
        acc1 += dv.y * bd[4 * k4 + 1];
        acc2 += dv.z * bd[4 * k4 + 2];
        acc3 += dv.w * bd[4 * k4 + 3];
      }
    }
    xs[1 - p][j] = (acc0 + acc1) + (acc2 + acc3);

    if (t < T_STEPS - 1) {
      if (tid < 64)       ymb[1 - p][tid]     = pf;
      else if (tid < 96)  ub[1 - p][tid - 64] = pf;
      else if (tid < 112) db[1 - p][tid - 96] = pf;
    }
    __syncthreads();
  }

  out[(size_t)b * NXX + j] = xs[0][j];
}

// ---------------------------------------------------------------------------
extern "C" void kernel_launch(void* const* d_in, const int* in_sizes, int n_in,
                              void* d_out, int out_size, void* d_ws,
                              size_t ws_size, hipStream_t stream) {
  const float* Yp  = (const float*)d_in[0];
  const float* Up  = (const float*)d_in[1];
  const float* Dp  = (const float*)d_in[2];
  const float* Wfx = (const float*)d_in[3];
  const float* bfx = (const float*)d_in[4];
  const float* Wfu = (const float*)d_in[5];
  const float* bfu = (const float*)d_in[6];
  const float* Wfd = (const float*)d_in[7];
  const float* bfd = (const float*)d_in[8];
  const float* Wfy = (const float*)d_in[9];
  const float* bfy = (const float*)d_in[10];
  const float* Q   = (const float*)d_in[11];
  const float* R   = (const float*)d_in[12];
  const float* P0  = (const float*)d_in[13];
  const float* x0  = (const float*)d_in[15];

  float* ws    = (float*)d_ws;
  float* Linf  = ws;                      // 128*64
  float* LinfT = Linf  + NXX * NYY;       // 64*128
  float* CWq   = LinfT + NYY * NXX;       // 128*64
  float* tmpA  = CWq   + NXX * NYY;       // 128*128
  float* tmpB  = tmpA  + NXX * NXX;       // 128*128
  float* Az    = tmpB  + NXX * NXX;       // 128*128
  float* Buz   = Az    + NXX * NXX;       // 32*128
  float* Bdz   = Buz   + NUU * NXX;       // 16*128
  float* cz    = Bdz   + NDD * NXX;       // 128
  float* pA    = cz    + NXX;             // 128*128 (A^2k ping)
  float* pB    = pA    + NXX * NXX;       // 128*128 (A^2k pong)
  float* V     = pB    + NXX * NXX;       // 256*32*128 = 4 MB

  const size_t needBytes =
      ((size_t)(V - ws) + (size_t)BATCH * NCH * NXX) * sizeof(float);

  lkf_gains<<<dim3(1), dim3(256), 0, stream>>>(Wfx, Wfy, Q, R, P0, Linf, LinfT,
                                               CWq, tmpA, tmpB);
  lkf_fuse<<<dim3(177), dim3(64), 0, stream>>>(Wfx, Wfu, Wfd, Wfy, bfx, bfu,
                                               bfd, bfy, Linf, Az, Buz, Bdz,
                                               cz);

  if (ws_size >= needBytes) {
    // A^64 by repeated squaring: Az->pA (A^2), ... , pA->pB (A^64)
    mat_sq<<<dim3(64), dim3(256), 0, stream>>>(Az, pA);
    mat_sq<<<dim3(64), dim3(256), 0, stream>>>(pA, pB);
    mat_sq<<<dim3(64), dim3(256), 0, stream>>>(pB, pA);
    mat_sq<<<dim3(64), dim3(256), 0, stream>>>(pA, pB);
    mat_sq<<<dim3(64), dim3(256), 0, stream>>>(pB, pA);
    mat_sq<<<dim3(64), dim3(256), 0, stream>>>(pA, pB);   // pB = A^64
    lkf_chunk<<<dim3(BATCH, NCH), dim3(256), 0, stream>>>(
        Yp, Up, Dp, Az, Buz, Bdz, cz, LinfT, V);
    lkf_comb<<<dim3(BATCH), dim3(128), 0, stream>>>(pB, V, x0, (float*)d_out);
  } else {
    lkf_state<<<dim3(BATCH), dim3(128), 0, stream>>>(
        Yp, Up, Dp, Az, Buz, Bdz, cz, LinfT, x0, (float*)d_out);
  }
}

// Round 4
// 2581.505 us; speedup vs baseline: 69.1470x; 1.0946x over previous
//
#include <hip/hip_runtime.h>

#define T_STEPS 2048
#define BATCH   256
#define NXX     128
#define NYY     64
#define NUU     32
#define NDD     16

#define CCH     64
#define NCH     (T_STEPS / CCH)   // 32 chunks

// XOR swizzle: conflict-free LDS for row- and column-pattern access.
#define SWZ(i, j) (((i) << 6) + ((j) ^ ((i) & 31)))

// For row r, aligned col-group cg (cg%4==0): elements [r][cg..cg+3] live in
// ONE contiguous aligned float4 at (r<<6) + (cg ^ (r&28)), with element
// (cg+b) at component (b ^ (r&3)).  All perms compile-time when r = base+a
// with base 4-aligned (then (r&3) == a).
__device__ __forceinline__ float4 ld4swz(const float* s, int row, int cg) {
  return *(const float4*)(s + (row << 6) + (cg ^ (row & 28)));
}
__device__ __forceinline__ void st4swz(float* s, int row, int cg, const float4& v) {
  *(float4*)(s + (row << 6) + (cg ^ (row & 28))) = v;
}

// ---------------------------------------------------------------------------
// K1: Riccati recursion -> converged gain L_inf (+ transposed copy).
// Exact inversion every iteration (round-0 algorithm; NS tracking broke
// convergence -> never re-introduce stateful approximate inverses).
// This round: Gauss-Jordan switched from 64 rank-1 pivots (128 barriers) to
// 16 block-steps of 4 pivots (32 barriers).  S is SPD -> diagonal 4x4 pivot
// blocks are SPD -> unpivoted register inversion is stable.
// ---------------------------------------------------------------------------
__global__ __launch_bounds__(256, 1)
void lkf_gains(const float* __restrict__ F, const float* __restrict__ W,
               const float* __restrict__ Q, const float* __restrict__ R,
               const float* __restrict__ P0, float* __restrict__ Linf,
               float* __restrict__ LinfT, float* __restrict__ CWq,
               float* __restrict__ tmpA, float* __restrict__ tmpB)
{
  __shared__ __align__(16) float sG[NXX * NYY];   // 32 KB (swizzled): G, later H
  __shared__ __align__(16) float sS[NYY * NYY];   // 16 KB (swizzled): S -> Sinv -> X
  __shared__ __align__(16) float sM[NYY * NYY];   // 16 KB (swizzled): M; aliased sRed
  __shared__ __align__(16) float sW[NXX * NYY];   // 32 KB (swizzled): W resident
  float* sRed = sM;
  const int tid = threadIdx.x;

  // ---------------- prologue ------------------------------------------------
  for (int idx = tid; idx < NXX * NYY; idx += 256)
    sW[SWZ(idx >> 6, idx & 63)] = W[idx];
  // tmpA = F^T W
  for (int idx = tid; idx < NXX * NYY; idx += 256) {
    const int k = idx >> 6, j = idx & 63;
    float acc = 0.f;
    for (int i = 0; i < NXX; ++i) acc += F[i * NXX + k] * W[i * NYY + j];
    tmpA[idx] = acc;
  }
  __syncthreads();
  // CWq = F (F^T W) + Q W
  for (int idx = tid; idx < NXX * NYY; idx += 256) {
    const int i = idx >> 6, j = idx & 63;
    float acc = 0.f;
    for (int k = 0; k < NXX; ++k) acc += F[i * NXX + k] * tmpA[k * NYY + j];
    for (int k = 0; k < NXX; ++k) acc += Q[i * NXX + k] * W[k * NYY + j];
    CWq[idx] = acc;
  }
  // tmpB = P0 @ F^T
  for (int idx = tid; idx < NXX * NXX; idx += 256) {
    const int i = idx >> 7, j = idx & 127;
    float acc = 0.f;
    for (int k = 0; k < NXX; ++k) acc += P0[i * NXX + k] * F[j * NXX + k];
    tmpB[idx] = acc;
  }
  __syncthreads();
  // tmpA = F @ tmpB + Q  (Pi_0)
  for (int idx = tid; idx < NXX * NXX; idx += 256) {
    const int i = idx >> 7, j = idx & 127;
    float acc = Q[idx];
    for (int k = 0; k < NXX; ++k) acc += F[i * NXX + k] * tmpB[k * NXX + j];
    tmpA[idx] = acc;
  }
  __syncthreads();
  // sG = Pi_0 @ W (swizzled)
  for (int idx = tid; idx < NXX * NYY; idx += 256) {
    const int i = idx >> 6, j = idx & 63;
    float acc = 0.f;
    for (int k = 0; k < NXX; ++k) acc += tmpA[i * NXX + k] * W[k * NYY + j];
    sG[SWZ(i, j)] = acc;
  }
  __syncthreads();
  // Ft for coalesced column access in (d)
  for (int idx = tid; idx < NXX * NXX; idx += 256)
    tmpB[idx] = F[(idx & 127) * NXX + (idx >> 7)];
  const float* Ft = tmpB;

  const int i16 = (tid >> 4) * 4;
  const int j16 = (tid & 15) * 4;
  const int i32 = (tid >> 3) * 4;
  const int j32 = (tid & 7) * 8;

  float cwq[4][8], rreg[4][4];
#pragma unroll
  for (int a = 0; a < 4; ++a)
#pragma unroll
    for (int b = 0; b < 8; ++b)
      cwq[a][b] = CWq[(i32 + a) * NYY + j32 + b];
#pragma unroll
  for (int a = 0; a < 4; ++a)
#pragma unroll
    for (int b = 0; b < 4; ++b)
      rreg[a][b] = R[(i16 + a) * NYY + j16 + b];

  float prevG[4][8], diff[4][8];
#pragma unroll
  for (int a = 0; a < 4; ++a)
#pragma unroll
    for (int b = 0; b < 8; ++b) { prevG[a][b] = 1e30f; diff[a][b] = 0.f; }
  int   cc = 0;
  bool  fin = false;
  float prevDelta = 1e30f;
  __syncthreads();

  // ---------------- main recursion -----------------------------------------
  for (int t = 0; t < T_STEPS; ++t) {
    // (a) S = R + W^T G   (float4 swizzled reads; same FMA set as scalar)
    {
      float acc[4][4];
#pragma unroll
      for (int a = 0; a < 4; ++a)
#pragma unroll
        for (int b = 0; b < 4; ++b) acc[a][b] = 0.f;
      for (int kb = 0; kb < NXX; kb += 4) {
#pragma unroll
        for (int kk = 0; kk < 4; ++kk) {
          const int k = kb + kk;
          const float4 wv = ld4swz(sW, k, i16);
          const float4 gv = ld4swz(sG, k, j16);
          const float* wf = (const float*)&wv;
          const float* gf = (const float*)&gv;
#pragma unroll
          for (int a = 0; a < 4; ++a)
#pragma unroll
            for (int b = 0; b < 4; ++b)
              acc[a][b] += wf[a ^ kk] * gf[b ^ kk];
        }
      }
#pragma unroll
      for (int a = 0; a < 4; ++a) {
        float4 w; float* wf = (float*)&w;
#pragma unroll
        for (int b = 0; b < 4; ++b) wf[b ^ a] = rreg[a][b] + acc[a][b];
        st4swz(sS, i16 + a, j16, w);
      }
    }
    __syncthreads();

    // (b) BLOCK Gauss-Jordan inversion of sS: 16 steps x 4 pivots.
    // Per block-step kb, with original values D=S[B,B], R=S[B,j], C=S[i,B]:
    //   S[B,B]=Dinv; S[B,j]=Dinv R; S[i,B]=-C Dinv; S[i,j]-=C Dinv R.
    // Equivalent to 4 sequential rank-1 GJ pivots (exact in infinite prec).
    for (int kb = 0; kb < NYY; kb += 4) {
      float d[4][4], r[4][4], cb[4][4], o[4][4];
#pragma unroll
      for (int a = 0; a < 4; ++a) {
        const float4 Dv = ld4swz(sS, kb + a, kb);
        const float4 Rv = ld4swz(sS, kb + a, j16);
        const float4 Cv = ld4swz(sS, i16 + a, kb);
        const float4 Ov = ld4swz(sS, i16 + a, j16);
        const float* Df = (const float*)&Dv;
        const float* Rf = (const float*)&Rv;
        const float* Cf = (const float*)&Cv;
        const float* Of = (const float*)&Ov;
#pragma unroll
        for (int b = 0; b < 4; ++b) {
          d[a][b]  = Df[b ^ a];
          r[a][b]  = Rf[b ^ a];
          cb[a][b] = Cf[b ^ a];
          o[a][b]  = Of[b ^ a];
        }
      }
      // Dinv in registers (unpivoted in-place GJ; D is SPD).
#pragma unroll
      for (int k = 0; k < 4; ++k) {
        const float p = 1.0f / d[k][k];
#pragma unroll
        for (int j = 0; j < 4; ++j) if (j != k) d[k][j] *= p;
        float cv[4];
#pragma unroll
        for (int i = 0; i < 4; ++i) cv[i] = d[i][k];
        d[k][k] = p;
#pragma unroll
        for (int i = 0; i < 4; ++i) if (i != k) {
#pragma unroll
          for (int j = 0; j < 4; ++j) if (j != k) d[i][j] -= cv[i] * d[k][j];
          d[i][k] = -cv[i] * p;
        }
      }
      // T = Dinv@R; U = C@Dinv; V = C@T
      float tT[4][4], uU[4][4], vV[4][4];
#pragma unroll
      for (int a = 0; a < 4; ++a)
#pragma unroll
        for (int b = 0; b < 4; ++b) {
          float s1 = 0.f, s2 = 0.f;
#pragma unroll
          for (int k = 0; k < 4; ++k) {
            s1 += d[a][k] * r[k][b];
            s2 += cb[a][k] * d[k][b];
          }
          tT[a][b] = s1; uU[a][b] = s2;
        }
#pragma unroll
      for (int a = 0; a < 4; ++a)
#pragma unroll
        for (int b = 0; b < 4; ++b) {
          float s = 0.f;
#pragma unroll
          for (int k = 0; k < 4; ++k) s += cb[a][k] * tT[k][b];
          vV[a][b] = s;
        }
      __syncthreads();   // all in-place reads complete before writes
      {
        const bool rowB = (i16 == kb), colB = (j16 == kb);
#pragma unroll
        for (int a = 0; a < 4; ++a) {
          float4 w; float* wf = (float*)&w;
#pragma unroll
          for (int b = 0; b < 4; ++b) {
            float val;
            if (rowB && colB)  val = d[a][b];
            else if (rowB)     val = tT[a][b];
            else if (colB)     val = -uU[a][b];
            else               val = o[a][b] - vV[a][b];
            wf[b ^ a] = val;
          }
          st4swz(sS, i16 + a, j16, w);
        }
      }
      __syncthreads();
    } // sS = Sinv

    // exit path: L_inf = G @ Sinv -> global (row-major + transposed), done.
    if (fin || t == T_STEPS - 1) {
      float acc[4][8];
#pragma unroll
      for (int a = 0; a < 4; ++a)
#pragma unroll
        for (int b = 0; b < 8; ++b) acc[a][b] = 0.f;
      for (int k = 0; k < NYY; ++k) {
        float g4[4], s8[8];
#pragma unroll
        for (int a = 0; a < 4; ++a) g4[a] = sG[SWZ(i32 + a, k)];
#pragma unroll
        for (int b = 0; b < 8; ++b) s8[b] = sS[SWZ(k, j32 + b)];
#pragma unroll
        for (int a = 0; a < 4; ++a)
#pragma unroll
          for (int b = 0; b < 8; ++b) acc[a][b] += g4[a] * s8[b];
      }
#pragma unroll
      for (int a = 0; a < 4; ++a)
#pragma unroll
        for (int b = 0; b < 8; ++b) {
          Linf[(i32 + a) * NYY + j32 + b]  = acc[a][b];
          LinfT[(j32 + b) * NXX + i32 + a] = acc[a][b];
        }
      break;
    }

    // (d) H = F @ G, overwrite sG  (Ft rows as global float4)
    {
      float acc[4][8];
#pragma unroll
      for (int a = 0; a < 4; ++a)
#pragma unroll
        for (int b = 0; b < 8; ++b) acc[a][b] = 0.f;
      for (int kb = 0; kb < NXX; kb += 4) {
#pragma unroll
        for (int kk = 0; kk < 4; ++kk) {
          const int k = kb + kk;
          const float4 fv  = *(const float4*)(Ft + k * NXX + i32);
          const float4 gv0 = ld4swz(sG, k, j32);
          const float4 gv1 = ld4swz(sG, k, j32 + 4);
          const float* ff  = (const float*)&fv;
          const float* gf0 = (const float*)&gv0;
          const float* gf1 = (const float*)&gv1;
#pragma unroll
          for (int a = 0; a < 4; ++a)
#pragma unroll
            for (int b = 0; b < 4; ++b) {
              acc[a][b]     += ff[a] * gf0[b ^ kk];
              acc[a][b + 4] += ff[a] * gf1[b ^ kk];
            }
        }
      }
      __syncthreads();
#pragma unroll
      for (int a = 0; a < 4; ++a) {
        float4 w0, w1; float* wf0 = (float*)&w0; float* wf1 = (float*)&w1;
#pragma unroll
        for (int b = 0; b < 4; ++b) {
          wf0[b ^ a] = acc[a][b];
          wf1[b ^ a] = acc[a][b + 4];
        }
        st4swz(sG, i32 + a, j32, w0);
        st4swz(sG, i32 + a, j32 + 4, w1);
      }
    }
    __syncthreads();

    // (e) M = H^T W -> sM
    {
      float acc[4][4];
#pragma unroll
      for (int a = 0; a < 4; ++a)
#pragma unroll
        for (int b = 0; b < 4; ++b) acc[a][b] = 0.f;
      for (int kb = 0; kb < NXX; kb += 4) {
#pragma unroll
        for (int kk = 0; kk < 4; ++kk) {
          const int k = kb + kk;
          const float4 hv = ld4swz(sG, k, i16);
          const float4 wv = ld4swz(sW, k, j16);
          const float* hf = (const float*)&hv;
          const float* wf = (const float*)&wv;
#pragma unroll
          for (int a = 0; a < 4; ++a)
#pragma unroll
            for (int b = 0; b < 4; ++b)
              acc[a][b] += hf[a ^ kk] * wf[b ^ kk];
        }
      }
#pragma unroll
      for (int a = 0; a < 4; ++a) {
        float4 w; float* wf = (float*)&w;
#pragma unroll
        for (int b = 0; b < 4; ++b) wf[b ^ a] = acc[a][b];
        st4swz(sM, i16 + a, j16, w);
      }
    }
    __syncthreads();

    // (f) X = Sinv @ M -> sS
    {
      float acc[4][4];
#pragma unroll
      for (int a = 0; a < 4; ++a)
#pragma unroll
        for (int b = 0; b < 4; ++b) acc[a][b] = 0.f;
      for (int kb = 0; kb < NYY; kb += 4) {
        float4 sv[4];
#pragma unroll
        for (int a = 0; a < 4; ++a) sv[a] = ld4swz(sS, i16 + a, kb);
#pragma unroll
        for (int kk = 0; kk < 4; ++kk) {
          const float4 mv = ld4swz(sM, kb + kk, j16);
          const float* mf = (const float*)&mv;
#pragma unroll
          for (int a = 0; a < 4; ++a) {
            const float s = ((const float*)&sv[a])[kk ^ a];
#pragma unroll
            for (int b = 0; b < 4; ++b)
              acc[a][b] += s * mf[b ^ kk];
          }
        }
      }
      __syncthreads();
#pragma unroll
      for (int a = 0; a < 4; ++a) {
        float4 w; float* wf = (float*)&w;
#pragma unroll
        for (int b = 0; b < 4; ++b) wf[b ^ a] = acc[a][b];
        st4swz(sS, i16 + a, j16, w);
      }
    }
    __syncthreads();

    // (g) G' = CWq - H @ X -> sG; delta + diff for Aitken
    float gdelta = 0.f;
    {
      float acc[4][8];
#pragma unroll
      for (int a = 0; a < 4; ++a)
#pragma unroll
        for (int b = 0; b < 8; ++b) acc[a][b] = 0.f;
      for (int kb = 0; kb < NYY; kb += 4) {
        float4 hv[4];
#pragma unroll
        for (int a = 0; a < 4; ++a) hv[a] = ld4swz(sG, i32 + a, kb);
#pragma unroll
        for (int kk = 0; kk < 4; ++kk) {
          const float4 xv0 = ld4swz(sS, kb + kk, j32);
          const float4 xv1 = ld4swz(sS, kb + kk, j32 + 4);
          const float* xf0 = (const float*)&xv0;
          const float* xf1 = (const float*)&xv1;
#pragma unroll
          for (int a = 0; a < 4; ++a) {
            const float h = ((const float*)&hv[a])[kk ^ a];
#pragma unroll
            for (int b = 0; b < 4; ++b) {
              acc[a][b]     += h * xf0[b ^ kk];
              acc[a][b + 4] += h * xf1[b ^ kk];
            }
          }
        }
      }
      __syncthreads();
#pragma unroll
      for (int a = 0; a < 4; ++a) {
        float4 w0, w1; float* wf0 = (float*)&w0; float* wf1 = (float*)&w1;
#pragma unroll
        for (int b = 0; b < 4; ++b) {
          const float g0 = cwq[a][b]     - acc[a][b];
          const float g1 = cwq[a][b + 4] - acc[a][b + 4];
          wf0[b ^ a] = g0;
          wf1[b ^ a] = g1;
          const float d0 = g0 - prevG[a][b];
          const float d1 = g1 - prevG[a][b + 4];
          diff[a][b] = d0; diff[a][b + 4] = d1;
          gdelta = fmaxf(gdelta, fmaxf(fabsf(d0), fabsf(d1)));
          prevG[a][b] = g0; prevG[a][b + 4] = g1;
        }
        st4swz(sG, i32 + a, j32, w0);
        st4swz(sG, i32 + a, j32 + 4, w1);
      }
    }
    __syncthreads();
    sRed[tid] = gdelta;
    __syncthreads();
    if (tid < 64) {
      float m = fmaxf(fmaxf(sRed[tid], sRed[tid + 64]),
                      fmaxf(sRed[tid + 128], sRed[tid + 192]));
#pragma unroll
      for (int off = 32; off >= 1; off >>= 1)
        m = fmaxf(m, __shfl_down(m, off));
      if (tid == 0) sRed[0] = m;
    }
    __syncthreads();
    const float delta = sRed[0];
    const float r     = delta / prevDelta;
    prevDelta = delta;
    cc = (delta < 3e-5f) ? cc + 1 : 0;
    if (cc >= 2) fin = true;
    __syncthreads();

    // Aitken delta^2 jump (uniform condition; self-correcting afterwards)
    if (!fin && t >= 40 && ((t - 8) & 31) == 0 && r > 0.5f && r < 0.99f) {
      const float alpha = fminf(r / (1.0f - r), 25.0f);
#pragma unroll
      for (int a = 0; a < 4; ++a)
#pragma unroll
        for (int b = 0; b < 8; ++b) {
          const float g = prevG[a][b] + alpha * diff[a][b];
          sG[SWZ(i32 + a, j32 + b)] = g;
          prevG[a][b] = g;
        }
      __syncthreads();
    }
  }
}

// ---------------------------------------------------------------------------
// K1b: fold L_inf into constant step matrices.
// ---------------------------------------------------------------------------
__global__ __launch_bounds__(64, 1)
void lkf_fuse(const float* __restrict__ F, const float* __restrict__ Wfu,
              const float* __restrict__ Wfd, const float* __restrict__ Wy,
              const float* __restrict__ bfx, const float* __restrict__ bfu,
              const float* __restrict__ bfd, const float* __restrict__ bfy,
              const float* __restrict__ Linf, float* __restrict__ Az,
              float* __restrict__ Buz, float* __restrict__ Bdz,
              float* __restrict__ cz)
{
  __shared__ float srow[NXX];
  __shared__ float fw[NYY];
  const int w = blockIdx.x, tid = threadIdx.x;

  for (int k = tid; k < NXX; k += 64) {
    float v;
    if (w < 128)      v = F[w * NXX + k];
    else if (w < 160) v = Wfu[(w - 128) * NXX + k];
    else if (w < 176) v = Wfd[(w - 160) * NXX + k];
    else              v = bfx[k] + bfu[k] + bfd[k];
    srow[k] = v;
  }
  __syncthreads();
  {
    const int m = tid;
    float acc = (w == 176) ? bfy[m] : 0.f;
    for (int k = 0; k < NXX; ++k) acc += srow[k] * Wy[k * NYY + m];
    fw[m] = acc;
  }
  __syncthreads();
  for (int j = tid; j < NXX; j += 64) {
    float s = 0.f;
    for (int m = 0; m < NYY; ++m) s += fw[m] * Linf[j * NYY + m];
    const float val = srow[j] - s;
    if (w < 128)      Az[w * NXX + j] = val;
    else if (w < 160) Buz[(w - 128) * NXX + j] = val;
    else if (w < 176) Bdz[(w - 160) * NXX + j] = val;
    else              cz[j] = val;
  }
}

// ---------------------------------------------------------------------------
// K1c: 128x128 matrix squaring (for A^64 via 6 repeated squarings).
// ---------------------------------------------------------------------------
__global__ __launch_bounds__(256, 1)
void mat_sq(const float* __restrict__ in, float* __restrict__ out)
{
  const int gid = blockIdx.x * 256 + threadIdx.x;  // grid 64 -> 16384 = 128*128
  const int i = gid >> 7, j = gid & 127;
  float acc = 0.f;
  for (int k = 0; k < NXX; ++k) acc += in[i * NXX + k] * in[k * NXX + j];
  out[gid] = acc;
}

// ---------------------------------------------------------------------------
// K2a: time-parallel chunk pass.  For chunk c of batch b compute
//   v_c via v <- v A + i_t (v_0 = 0), i_t = u_t Bu + d_t Bd + ym_t L^T + c.
// This round: ALL 64 steps' inputs staged to LDS up front (28 KB) ->
// the step loop has ZERO global traffic (was HBM-latency-bound: each step
// chained a ~900cy load-commit into its barrier).  2 barriers/step (h-split
// partial reduction), ~3 blocks/CU resident, VALU-bound at ~205 us floor.
// ---------------------------------------------------------------------------
__global__ __launch_bounds__(256, 2)
void lkf_chunk(const float* __restrict__ Yp, const float* __restrict__ Up,
               const float* __restrict__ Dp, const float* __restrict__ Az,
               const float* __restrict__ Buz, const float* __restrict__ Bdz,
               const float* __restrict__ cz, const float* __restrict__ LinfT,
               float* __restrict__ V)
{
  __shared__ __align__(16) float4 inL[1792];      // ym 1024 | u 512 | d 256 (28 KB)
  __shared__ __align__(16) float xs[2][NXX];
  __shared__ float ps[NXX];

  const int tid = threadIdx.x;
  const int b   = blockIdx.x;       // batch
  const int c   = blockIdx.y;       // chunk
  const int j   = tid & 127;
  const int h   = tid >> 7;         // k-half

  float a[64], l[32], bu[16], bd[8];
#pragma unroll
  for (int k = 0; k < 64; ++k) a[k] = Az[(h * 64 + k) * NXX + j];
#pragma unroll
  for (int m = 0; m < 32; ++m) l[m] = LinfT[(h * 32 + m) * NXX + j];
#pragma unroll
  for (int k = 0; k < 16; ++k) bu[k] = Buz[(h * 16 + k) * NXX + j];
#pragma unroll
  for (int k = 0; k < 8; ++k)  bd[k] = Bdz[(h * 8 + k) * NXX + j];
  const float cj = (h == 0) ? cz[j] : 0.f;

  const int t0 = c * CCH;
  // ---- stage the whole chunk's inputs (7 coalesced float4 per thread) ----
  {
    const float4* Y4 = (const float4*)Yp;
    const float4* U4 = (const float4*)Up;
    const float4* D4 = (const float4*)Dp;
#pragma unroll
    for (int q = 0; q < 7; ++q) {
      const int idx = q * 256 + tid;
      float4 v;
      if (q < 4) {                       // ym region: idx in [0,1024)
        const int s = idx >> 4, f = idx & 15;
        v = Y4[((size_t)(t0 + s) * BATCH + b) * (NYY / 4) + f];
      } else if (q < 6) {                // u region: idx in [1024,1536)
        const int rel = idx - 1024, s = rel >> 3, f = rel & 7;
        v = U4[((size_t)(t0 + s) * BATCH + b) * (NUU / 4) + f];
      } else {                           // d region: idx in [1536,1792)
        const int rel = idx - 1536, s = rel >> 2, f = rel & 3;
        v = D4[((size_t)(t0 + s) * BATCH + b) * (NDD / 4) + f];
      }
      inL[idx] = v;
    }
  }
  if (tid < 128) xs[0][tid] = 0.f;
  __syncthreads();

  for (int s = 0; s < CCH; ++s) {
    const int p = s & 1;
    float acc0 = cj, acc1 = 0.f, acc2 = 0.f, acc3 = 0.f;
    {
      const float4* x4 = (const float4*)(xs[p] + h * 64);
#pragma unroll
      for (int k4 = 0; k4 < 16; ++k4) {
        const float4 xv = x4[k4];
        acc0 += xv.x * a[4 * k4 + 0];
        acc1 += xv.y * a[4 * k4 + 1];
        acc2 += xv.z * a[4 * k4 + 2];
        acc3 += xv.w * a[4 * k4 + 3];
      }
      const float4* y4 = inL + s * 16 + h * 8;
#pragma unroll
      for (int m4 = 0; m4 < 8; ++m4) {
        const float4 yv = y4[m4];
        acc0 += yv.x * l[4 * m4 + 0];
        acc1 += yv.y * l[4 * m4 + 1];
        acc2 += yv.z * l[4 * m4 + 2];
        acc3 += yv.w * l[4 * m4 + 3];
      }
      const float4* u4 = inL + 1024 + s * 8 + h * 4;
#pragma unroll
      for (int k4 = 0; k4 < 4; ++k4) {
        const float4 uv = u4[k4];
        acc0 += uv.x * bu[4 * k4 + 0];
        acc1 += uv.y * bu[4 * k4 + 1];
        acc2 += uv.z * bu[4 * k4 + 2];
        acc3 += uv.w * bu[4 * k4 + 3];
      }
      const float4* d4 = inL + 1536 + s * 4 + h * 2;
#pragma unroll
      for (int k4 = 0; k4 < 2; ++k4) {
        const float4 dv = d4[k4];
        acc0 += dv.x * bd[4 * k4 + 0];
        acc1 += dv.y * bd[4 * k4 + 1];
        acc2 += dv.z * bd[4 * k4 + 2];
        acc3 += dv.w * bd[4 * k4 + 3];
      }
    }
    const float part = (acc0 + acc1) + (acc2 + acc3);
    if (h == 1) ps[j] = part;
    __syncthreads();
    if (h == 0) xs[1 - p][j] = part + ps[j];
    __syncthreads();
  }

  if (tid < 128)
    V[((size_t)b * NCH + c) * NXX + tid] = xs[0][tid];   // CCH even -> xs[0]
}

// ---------------------------------------------------------------------------
// K2b: serial chunk combine:  x <- x A^64 + v_c,  c = 0..NCH-1; out = x.
// ---------------------------------------------------------------------------
__global__ __launch_bounds__(128, 1)
void lkf_comb(const float* __restrict__ A64, const float* __restrict__ V,
              const float* __restrict__ x0, float* __restrict__ out)
{
  __shared__ __align__(16) float xs[2][NXX];
  const int tid = threadIdx.x;
  const int b   = blockIdx.x;
  float a[NXX];
#pragma unroll
  for (int k = 0; k < NXX; ++k) a[k] = A64[k * NXX + tid];
  xs[0][tid] = x0[tid];
  __syncthreads();
  for (int c = 0; c < NCH; ++c) {
    const int p = c & 1;
    float acc0 = V[((size_t)b * NCH + c) * NXX + tid];
    float acc1 = 0.f, acc2 = 0.f, acc3 = 0.f;
    const float4* x4 = (const float4*)xs[p];
#pragma unroll
    for (int k4 = 0; k4 < NXX / 4; ++k4) {
      const float4 xv = x4[k4];
      acc0 += xv.x * a[4 * k4 + 0];
      acc1 += xv.y * a[4 * k4 + 1];
      acc2 += xv.z * a[4 * k4 + 2];
      acc3 += xv.w * a[4 * k4 + 3];
    }
    xs[1 - p][tid] = (acc0 + acc1) + (acc2 + acc3);
    __syncthreads();
  }
  out[(size_t)b * NXX + tid] = xs[0][tid];   // NCH even -> xs[0]
}

// ---------------------------------------------------------------------------
// K2 (fallback): fully serial state recursion; used only when the workspace
// is too small for the chunk path.
// ---------------------------------------------------------------------------
__global__ __launch_bounds__(128, 1)
void lkf_state(const float* __restrict__ Yp, const float* __restrict__ Up,
               const float* __restrict__ Dp, const float* __restrict__ Az,
               const float* __restrict__ Buz, const float* __restrict__ Bdz,
               const float* __restrict__ cz, const float* __restrict__ LinfT,
               const float* __restrict__ x0, float* __restrict__ out)
{
  __shared__ __align__(16) float xs[2][NXX];
  __shared__ __align__(16) float ymb[2][NYY];
  __shared__ __align__(16) float ub[2][NUU];
  __shared__ __align__(16) float db[2][NDD];

  const int tid = threadIdx.x;
  const int b   = blockIdx.x;
  const int j   = tid;

  float a[NXX], l[NYY], bu[NUU], bd[NDD];
#pragma unroll
  for (int k = 0; k < NXX; ++k) a[k] = Az[k * NXX + j];
#pragma unroll
  for (int m = 0; m < NYY; ++m) l[m] = LinfT[m * NXX + j];
#pragma unroll
  for (int k = 0; k < NUU; ++k) bu[k] = Buz[k * NXX + j];
#pragma unroll
  for (int k = 0; k < NDD; ++k) bd[k] = Bdz[k * NXX + j];
  const float cj = cz[j];

  xs[0][tid] = x0[tid];
  if (tid < 64)       ymb[0][tid]     = Yp[(size_t)b * NYY + tid];
  else if (tid < 96)  ub[0][tid - 64] = Up[(size_t)b * NUU + (tid - 64)];
  else if (tid < 112) db[0][tid - 96] = Dp[(size_t)b * NDD + (tid - 96)];
  __syncthreads();

  for (int t = 0; t < T_STEPS; ++t) {
    const int p = t & 1;
    float pf = 0.f;
    if (t < T_STEPS - 1) {
      const size_t tb = (size_t)(t + 1) * BATCH + b;
      if (tid < 64)       pf = Yp[tb * NYY + tid];
      else if (tid < 96)  pf = Up[tb * NUU + (tid - 64)];
      else if (tid < 112) pf = Dp[tb * NDD + (tid - 96)];
    }

    float acc0 = cj, acc1 = 0.f, acc2 = 0.f, acc3 = 0.f;
    {
      const float4* x4 = (const float4*)xs[p];
#pragma unroll
      for (int k4 = 0; k4 < NXX / 4; ++k4) {
        const float4 xv = x4[k4];
        acc0 += xv.x * a[4 * k4 + 0];
        acc1 += xv.y * a[4 * k4 + 1];
        acc2 += xv.z * a[4 * k4 + 2];
        acc3 += xv.w * a[4 * k4 + 3];
      }
      const float4* y4 = (const float4*)ymb[p];
#pragma unroll
      for (int m4 = 0; m4 < NYY / 4; ++m4) {
        const float4 yv = y4[m4];
        acc0 += yv.x * l[4 * m4 + 0];
        acc1 += yv.y * l[4 * m4 + 1];
        acc2 += yv.z * l[4 * m4 + 2];
        acc3 += yv.w * l[4 * m4 + 3];
      }
      const float4* u4 = (const float4*)ub[p];
#pragma unroll
      for (int k4 = 0; k4 < NUU / 4; ++k4) {
        const float4 uv = u4[k4];
        acc0 += uv.x * bu[4 * k4 + 0];
        acc1 += uv.y * bu[4 * k4 + 1];
        acc2 += uv.z * bu[4 * k4 + 2];
        acc3 += uv.w * bu[4 * k4 + 3];
      }
      const float4* d4 = (const float4*)db[p];
#pragma unroll
      for (int k4 = 0; k4 < NDD / 4; ++k4) {
        const float4 dv = d4[k4];
        acc0 += dv.x * bd[4 * k4 + 0];
        acc1 += dv.y * bd[4 * k4 + 1];
        acc2 += dv.z * bd[4 * k4 + 2];
        acc3 += dv.w * bd[4 * k4 + 3];
      }
    }
    xs[1 - p][j] = (acc0 + acc1) + (acc2 + acc3);

    if (t < T_STEPS - 1) {
      if (tid < 64)       ymb[1 - p][tid]     = pf;
      else if (tid < 96)  ub[1 - p][tid - 64] = pf;
      else if (tid < 112) db[1 - p][tid - 96] = pf;
    }
    __syncthreads();
  }

  out[(size_t)b * NXX + j] = xs[0][j];
}

// ---------------------------------------------------------------------------
extern "C" void kernel_launch(void* const* d_in, const int* in_sizes, int n_in,
                              void* d_out, int out_size, void* d_ws,
                              size_t ws_size, hipStream_t stream) {
  const float* Yp  = (const float*)d_in[0];
  const float* Up  = (const float*)d_in[1];
  const float* Dp  = (const float*)d_in[2];
  const float* Wfx = (const float*)d_in[3];
  const float* bfx = (const float*)d_in[4];
  const float* Wfu = (const float*)d_in[5];
  const float* bfu = (const float*)d_in[6];
  const float* Wfd = (const float*)d_in[7];
  const float* bfd = (const float*)d_in[8];
  const float* Wfy = (const float*)d_in[9];
  const float* bfy = (const float*)d_in[10];
  const float* Q   = (const float*)d_in[11];
  const float* R   = (const float*)d_in[12];
  const float* P0  = (const float*)d_in[13];
  const float* x0  = (const float*)d_in[15];

  float* ws    = (float*)d_ws;
  float* Linf  = ws;                      // 128*64
  float* LinfT = Linf  + NXX * NYY;       // 64*128
  float* CWq   = LinfT + NYY * NXX;       // 128*64
  float* tmpA  = CWq   + NXX * NYY;       // 128*128
  float* tmpB  = tmpA  + NXX * NXX;       // 128*128
  float* Az    = tmpB  + NXX * NXX;       // 128*128
  float* Buz   = Az    + NXX * NXX;       // 32*128
  float* Bdz   = Buz   + NUU * NXX;       // 16*128
  float* cz    = Bdz   + NDD * NXX;       // 128
  float* pA    = cz    + NXX;             // 128*128 (A^2k ping)
  float* pB    = pA    + NXX * NXX;       // 128*128 (A^2k pong)
  float* V     = pB    + NXX * NXX;       // 256*32*128 = 4 MB

  const size_t needBytes =
      ((size_t)(V - ws) + (size_t)BATCH * NCH * NXX) * sizeof(float);

  lkf_gains<<<dim3(1), dim3(256), 0, stream>>>(Wfx, Wfy, Q, R, P0, Linf, LinfT,
                                               CWq, tmpA, tmpB);
  lkf_fuse<<<dim3(177), dim3(64), 0, stream>>>(Wfx, Wfu, Wfd, Wfy, bfx, bfu,
                                               bfd, bfy, Linf, Az, Buz, Bdz,
                                               cz);

  if (ws_size >= needBytes) {
    // A^64 by repeated squaring: Az->pA (A^2), ... , pA->pB (A^64)
    mat_sq<<<dim3(64), dim3(256), 0, stream>>>(Az, pA);
    mat_sq<<<dim3(64), dim3(256), 0, stream>>>(pA, pB);
    mat_sq<<<dim3(64), dim3(256), 0, stream>>>(pB, pA);
    mat_sq<<<dim3(64), dim3(256), 0, stream>>>(pA, pB);
    mat_sq<<<dim3(64), dim3(256), 0, stream>>>(pB, pA);
    mat_sq<<<dim3(64), dim3(256), 0, stream>>>(pA, pB);   // pB = A^64
    lkf_chunk<<<dim3(BATCH, NCH), dim3(256), 0, stream>>>(
        Yp, Up, Dp, Az, Buz, Bdz, cz, LinfT, V);
    lkf_comb<<<dim3(BATCH), dim3(128), 0, stream>>>(pB, V, x0, (float*)d_out);
  } else {
    lkf_state<<<dim3(BATCH), dim3(128), 0, stream>>>(
        Yp, Up, Dp, Az, Buz, Bdz, cz, LinfT, x0, (float*)d_out);
  }
}

// Round 5
// 2467.634 us; speedup vs baseline: 72.3378x; 1.0461x over previous
//
#include <hip/hip_runtime.h>

#define T_STEPS 2048
#define BATCH   256
#define NXX     128
#define NYY     64
#define NUU     32
#define NDD     16

#define CCH     64
#define NCH     (T_STEPS / CCH)   // 32 chunks

// XOR swizzle: conflict-free LDS for row- and column-pattern access.
#define SWZ(i, j) (((i) << 6) + ((j) ^ ((i) & 31)))

// For row r, aligned col-group cg (cg%4==0): elements [r][cg..cg+3] live in
// ONE contiguous aligned float4 at (r<<6) + (cg ^ (r&28)), with element
// (cg+b) at component (b ^ (r&3)).  All perms compile-time when r = base+a
// with base 4-aligned (then (r&3) == a).
__device__ __forceinline__ float4 ld4swz(const float* s, int row, int cg) {
  return *(const float4*)(s + (row << 6) + (cg ^ (row & 28)));
}
__device__ __forceinline__ void st4swz(float* s, int row, int cg, const float4& v) {
  *(float4*)(s + (row << 6) + (cg ^ (row & 28))) = v;
}

// ---------------------------------------------------------------------------
// K1: Riccati recursion -> converged gain L_inf (+ transposed copy).
// Exact inversion every iteration (round-0 algorithm; NS tracking broke
// convergence -> never re-introduce stateful approximate inverses).
// This round: (1) W reads in phases (a)/(e) moved from LDS to GLOBAL
// (L1/L2-resident, idle vmem pipe) -- the kernel is LDS-issue-bound, this
// removes ~36% of LDS traffic; (2) Aitken every 16 steps (t>=40).
// ---------------------------------------------------------------------------
__global__ __launch_bounds__(256, 1)
void lkf_gains(const float* __restrict__ F, const float* __restrict__ W,
               const float* __restrict__ Q, const float* __restrict__ R,
               const float* __restrict__ P0, float* __restrict__ Linf,
               float* __restrict__ LinfT, float* __restrict__ CWq,
               float* __restrict__ tmpA, float* __restrict__ tmpB)
{
  __shared__ __align__(16) float sG[NXX * NYY];   // 32 KB (swizzled): G, later H
  __shared__ __align__(16) float sS[NYY * NYY];   // 16 KB (swizzled): S -> Sinv -> X
  __shared__ __align__(16) float sM[NYY * NYY];   // 16 KB (swizzled): M; aliased sRed
  float* sRed = sM;
  const int tid = threadIdx.x;

  // ---------------- prologue ------------------------------------------------
  // tmpA = F^T W
  for (int idx = tid; idx < NXX * NYY; idx += 256) {
    const int k = idx >> 6, j = idx & 63;
    float acc = 0.f;
    for (int i = 0; i < NXX; ++i) acc += F[i * NXX + k] * W[i * NYY + j];
    tmpA[idx] = acc;
  }
  __syncthreads();
  // CWq = F (F^T W) + Q W
  for (int idx = tid; idx < NXX * NYY; idx += 256) {
    const int i = idx >> 6, j = idx & 63;
    float acc = 0.f;
    for (int k = 0; k < NXX; ++k) acc += F[i * NXX + k] * tmpA[k * NYY + j];
    for (int k = 0; k < NXX; ++k) acc += Q[i * NXX + k] * W[k * NYY + j];
    CWq[idx] = acc;
  }
  // tmpB = P0 @ F^T
  for (int idx = tid; idx < NXX * NXX; idx += 256) {
    const int i = idx >> 7, j = idx & 127;
    float acc = 0.f;
    for (int k = 0; k < NXX; ++k) acc += P0[i * NXX + k] * F[j * NXX + k];
    tmpB[idx] = acc;
  }
  __syncthreads();
  // tmpA = F @ tmpB + Q  (Pi_0)
  for (int idx = tid; idx < NXX * NXX; idx += 256) {
    const int i = idx >> 7, j = idx & 127;
    float acc = Q[idx];
    for (int k = 0; k < NXX; ++k) acc += F[i * NXX + k] * tmpB[k * NXX + j];
    tmpA[idx] = acc;
  }
  __syncthreads();
  // sG = Pi_0 @ W (swizzled)
  for (int idx = tid; idx < NXX * NYY; idx += 256) {
    const int i = idx >> 6, j = idx & 63;
    float acc = 0.f;
    for (int k = 0; k < NXX; ++k) acc += tmpA[i * NXX + k] * W[k * NYY + j];
    sG[SWZ(i, j)] = acc;
  }
  __syncthreads();
  // Ft for coalesced column access in (d)
  for (int idx = tid; idx < NXX * NXX; idx += 256)
    tmpB[idx] = F[(idx & 127) * NXX + (idx >> 7)];
  const float* Ft = tmpB;

  const int i16 = (tid >> 4) * 4;
  const int j16 = (tid & 15) * 4;
  const int i32 = (tid >> 3) * 4;
  const int j32 = (tid & 7) * 8;

  float cwq[4][8], rreg[4][4];
#pragma unroll
  for (int a = 0; a < 4; ++a)
#pragma unroll
    for (int b = 0; b < 8; ++b)
      cwq[a][b] = CWq[(i32 + a) * NYY + j32 + b];
#pragma unroll
  for (int a = 0; a < 4; ++a)
#pragma unroll
    for (int b = 0; b < 4; ++b)
      rreg[a][b] = R[(i16 + a) * NYY + j16 + b];

  float prevG[4][8], diff[4][8];
#pragma unroll
  for (int a = 0; a < 4; ++a)
#pragma unroll
    for (int b = 0; b < 8; ++b) { prevG[a][b] = 1e30f; diff[a][b] = 0.f; }
  int   cc = 0;
  bool  fin = false;
  float prevDelta = 1e30f;
  __syncthreads();

  // ---------------- main recursion -----------------------------------------
  for (int t = 0; t < T_STEPS; ++t) {
    // (a) S = R + W^T G   (W from GLOBAL: natural order; G from LDS swizzled)
    {
      float acc[4][4];
#pragma unroll
      for (int a = 0; a < 4; ++a)
#pragma unroll
        for (int b = 0; b < 4; ++b) acc[a][b] = 0.f;
      for (int kb = 0; kb < NXX; kb += 4) {
#pragma unroll
        for (int kk = 0; kk < 4; ++kk) {
          const int k = kb + kk;
          const float4 wv = *(const float4*)(W + k * NYY + i16);
          const float4 gv = ld4swz(sG, k, j16);
          const float* wf = (const float*)&wv;
          const float* gf = (const float*)&gv;
#pragma unroll
          for (int a = 0; a < 4; ++a)
#pragma unroll
            for (int b = 0; b < 4; ++b)
              acc[a][b] += wf[a] * gf[b ^ kk];
        }
      }
#pragma unroll
      for (int a = 0; a < 4; ++a) {
        float4 w; float* wf = (float*)&w;
#pragma unroll
        for (int b = 0; b < 4; ++b) wf[b ^ a] = rreg[a][b] + acc[a][b];
        st4swz(sS, i16 + a, j16, w);
      }
    }
    __syncthreads();

    // (b) BLOCK Gauss-Jordan inversion of sS: 16 steps x 4 pivots.
    for (int kb = 0; kb < NYY; kb += 4) {
      float d[4][4], r[4][4], cb[4][4], o[4][4];
#pragma unroll
      for (int a = 0; a < 4; ++a) {
        const float4 Dv = ld4swz(sS, kb + a, kb);
        const float4 Rv = ld4swz(sS, kb + a, j16);
        const float4 Cv = ld4swz(sS, i16 + a, kb);
        const float4 Ov = ld4swz(sS, i16 + a, j16);
        const float* Df = (const float*)&Dv;
        const float* Rf = (const float*)&Rv;
        const float* Cf = (const float*)&Cv;
        const float* Of = (const float*)&Ov;
#pragma unroll
        for (int b = 0; b < 4; ++b) {
          d[a][b]  = Df[b ^ a];
          r[a][b]  = Rf[b ^ a];
          cb[a][b] = Cf[b ^ a];
          o[a][b]  = Of[b ^ a];
        }
      }
      // Dinv in registers (unpivoted in-place GJ; D is SPD).
#pragma unroll
      for (int k = 0; k < 4; ++k) {
        const float p = 1.0f / d[k][k];
#pragma unroll
        for (int j = 0; j < 4; ++j) if (j != k) d[k][j] *= p;
        float cv[4];
#pragma unroll
        for (int i = 0; i < 4; ++i) cv[i] = d[i][k];
        d[k][k] = p;
#pragma unroll
        for (int i = 0; i < 4; ++i) if (i != k) {
#pragma unroll
          for (int j = 0; j < 4; ++j) if (j != k) d[i][j] -= cv[i] * d[k][j];
          d[i][k] = -cv[i] * p;
        }
      }
      // T = Dinv@R; U = C@Dinv; V = C@T
      float tT[4][4], uU[4][4], vV[4][4];
#pragma unroll
      for (int a = 0; a < 4; ++a)
#pragma unroll
        for (int b = 0; b < 4; ++b) {
          float s1 = 0.f, s2 = 0.f;
#pragma unroll
          for (int k = 0; k < 4; ++k) {
            s1 += d[a][k] * r[k][b];
            s2 += cb[a][k] * d[k][b];
          }
          tT[a][b] = s1; uU[a][b] = s2;
        }
#pragma unroll
      for (int a = 0; a < 4; ++a)
#pragma unroll
        for (int b = 0; b < 4; ++b) {
          float s = 0.f;
#pragma unroll
          for (int k = 0; k < 4; ++k) s += cb[a][k] * tT[k][b];
          vV[a][b] = s;
        }
      __syncthreads();   // all in-place reads complete before writes
      {
        const bool rowB = (i16 == kb), colB = (j16 == kb);
#pragma unroll
        for (int a = 0; a < 4; ++a) {
          float4 w; float* wf = (float*)&w;
#pragma unroll
          for (int b = 0; b < 4; ++b) {
            float val;
            if (rowB && colB)  val = d[a][b];
            else if (rowB)     val = tT[a][b];
            else if (colB)     val = -uU[a][b];
            else               val = o[a][b] - vV[a][b];
            wf[b ^ a] = val;
          }
          st4swz(sS, i16 + a, j16, w);
        }
      }
      __syncthreads();
    } // sS = Sinv

    // exit path: L_inf = G @ Sinv -> global (row-major + transposed), done.
    if (fin || t == T_STEPS - 1) {
      float acc[4][8];
#pragma unroll
      for (int a = 0; a < 4; ++a)
#pragma unroll
        for (int b = 0; b < 8; ++b) acc[a][b] = 0.f;
      for (int k = 0; k < NYY; ++k) {
        float g4[4], s8[8];
#pragma unroll
        for (int a = 0; a < 4; ++a) g4[a] = sG[SWZ(i32 + a, k)];
#pragma unroll
        for (int b = 0; b < 8; ++b) s8[b] = sS[SWZ(k, j32 + b)];
#pragma unroll
        for (int a = 0; a < 4; ++a)
#pragma unroll
          for (int b = 0; b < 8; ++b) acc[a][b] += g4[a] * s8[b];
      }
#pragma unroll
      for (int a = 0; a < 4; ++a)
#pragma unroll
        for (int b = 0; b < 8; ++b) {
          Linf[(i32 + a) * NYY + j32 + b]  = acc[a][b];
          LinfT[(j32 + b) * NXX + i32 + a] = acc[a][b];
        }
      break;
    }

    // (d) H = F @ G, overwrite sG  (Ft rows as global float4)
    {
      float acc[4][8];
#pragma unroll
      for (int a = 0; a < 4; ++a)
#pragma unroll
        for (int b = 0; b < 8; ++b) acc[a][b] = 0.f;
      for (int kb = 0; kb < NXX; kb += 4) {
#pragma unroll
        for (int kk = 0; kk < 4; ++kk) {
          const int k = kb + kk;
          const float4 fv  = *(const float4*)(Ft + k * NXX + i32);
          const float4 gv0 = ld4swz(sG, k, j32);
          const float4 gv1 = ld4swz(sG, k, j32 + 4);
          const float* ff  = (const float*)&fv;
          const float* gf0 = (const float*)&gv0;
          const float* gf1 = (const float*)&gv1;
#pragma unroll
          for (int a = 0; a < 4; ++a)
#pragma unroll
            for (int b = 0; b < 4; ++b) {
              acc[a][b]     += ff[a] * gf0[b ^ kk];
              acc[a][b + 4] += ff[a] * gf1[b ^ kk];
            }
        }
      }
      __syncthreads();
#pragma unroll
      for (int a = 0; a < 4; ++a) {
        float4 w0, w1; float* wf0 = (float*)&w0; float* wf1 = (float*)&w1;
#pragma unroll
        for (int b = 0; b < 4; ++b) {
          wf0[b ^ a] = acc[a][b];
          wf1[b ^ a] = acc[a][b + 4];
        }
        st4swz(sG, i32 + a, j32, w0);
        st4swz(sG, i32 + a, j32 + 4, w1);
      }
    }
    __syncthreads();

    // (e) M = H^T W -> sM   (W from GLOBAL)
    {
      float acc[4][4];
#pragma unroll
      for (int a = 0; a < 4; ++a)
#pragma unroll
        for (int b = 0; b < 4; ++b) acc[a][b] = 0.f;
      for (int kb = 0; kb < NXX; kb += 4) {
#pragma unroll
        for (int kk = 0; kk < 4; ++kk) {
          const int k = kb + kk;
          const float4 hv = ld4swz(sG, k, i16);
          const float4 wv = *(const float4*)(W + k * NYY + j16);
          const float* hf = (const float*)&hv;
          const float* wf = (const float*)&wv;
#pragma unroll
          for (int a = 0; a < 4; ++a)
#pragma unroll
            for (int b = 0; b < 4; ++b)
              acc[a][b] += hf[a ^ kk] * wf[b];
        }
      }
#pragma unroll
      for (int a = 0; a < 4; ++a) {
        float4 w; float* wf = (float*)&w;
#pragma unroll
        for (int b = 0; b < 4; ++b) wf[b ^ a] = acc[a][b];
        st4swz(sM, i16 + a, j16, w);
      }
    }
    __syncthreads();

    // (f) X = Sinv @ M -> sS
    {
      float acc[4][4];
#pragma unroll
      for (int a = 0; a < 4; ++a)
#pragma unroll
        for (int b = 0; b < 4; ++b) acc[a][b] = 0.f;
      for (int kb = 0; kb < NYY; kb += 4) {
        float4 sv[4];
#pragma unroll
        for (int a = 0; a < 4; ++a) sv[a] = ld4swz(sS, i16 + a, kb);
#pragma unroll
        for (int kk = 0; kk < 4; ++kk) {
          const float4 mv = ld4swz(sM, kb + kk, j16);
          const float* mf = (const float*)&mv;
#pragma unroll
          for (int a = 0; a < 4; ++a) {
            const float s = ((const float*)&sv[a])[kk ^ a];
#pragma unroll
            for (int b = 0; b < 4; ++b)
              acc[a][b] += s * mf[b ^ kk];
          }
        }
      }
      __syncthreads();
#pragma unroll
      for (int a = 0; a < 4; ++a) {
        float4 w; float* wf = (float*)&w;
#pragma unroll
        for (int b = 0; b < 4; ++b) wf[b ^ a] = acc[a][b];
        st4swz(sS, i16 + a, j16, w);
      }
    }
    __syncthreads();

    // (g) G' = CWq - H @ X -> sG; delta + diff for Aitken
    float gdelta = 0.f;
    {
      float acc[4][8];
#pragma unroll
      for (int a = 0; a < 4; ++a)
#pragma unroll
        for (int b = 0; b < 8; ++b) acc[a][b] = 0.f;
      for (int kb = 0; kb < NYY; kb += 4) {
        float4 hv[4];
#pragma unroll
        for (int a = 0; a < 4; ++a) hv[a] = ld4swz(sG, i32 + a, kb);
#pragma unroll
        for (int kk = 0; kk < 4; ++kk) {
          const float4 xv0 = ld4swz(sS, kb + kk, j32);
          const float4 xv1 = ld4swz(sS, kb + kk, j32 + 4);
          const float* xf0 = (const float*)&xv0;
          const float* xf1 = (const float*)&xv1;
#pragma unroll
          for (int a = 0; a < 4; ++a) {
            const float h = ((const float*)&hv[a])[kk ^ a];
#pragma unroll
            for (int b = 0; b < 4; ++b) {
              acc[a][b]     += h * xf0[b ^ kk];
              acc[a][b + 4] += h * xf1[b ^ kk];
            }
          }
        }
      }
      __syncthreads();
#pragma unroll
      for (int a = 0; a < 4; ++a) {
        float4 w0, w1; float* wf0 = (float*)&w0; float* wf1 = (float*)&w1;
#pragma unroll
        for (int b = 0; b < 4; ++b) {
          const float g0 = cwq[a][b]     - acc[a][b];
          const float g1 = cwq[a][b + 4] - acc[a][b + 4];
          wf0[b ^ a] = g0;
          wf1[b ^ a] = g1;
          const float d0 = g0 - prevG[a][b];
          const float d1 = g1 - prevG[a][b + 4];
          diff[a][b] = d0; diff[a][b + 4] = d1;
          gdelta = fmaxf(gdelta, fmaxf(fabsf(d0), fabsf(d1)));
          prevG[a][b] = g0; prevG[a][b + 4] = g1;
        }
        st4swz(sG, i32 + a, j32, w0);
        st4swz(sG, i32 + a, j32 + 4, w1);
      }
    }
    __syncthreads();
    sRed[tid] = gdelta;
    __syncthreads();
    if (tid < 64) {
      float m = fmaxf(fmaxf(sRed[tid], sRed[tid + 64]),
                      fmaxf(sRed[tid + 128], sRed[tid + 192]));
#pragma unroll
      for (int off = 32; off >= 1; off >>= 1)
        m = fmaxf(m, __shfl_down(m, off));
      if (tid == 0) sRed[0] = m;
    }
    __syncthreads();
    const float delta = sRed[0];
    const float r     = delta / prevDelta;
    prevDelta = delta;
    cc = (delta < 3e-5f) ? cc + 1 : 0;
    if (cc >= 2) fin = true;
    __syncthreads();

    // Aitken delta^2 jump, every 16 steps from t>=40 (uniform condition;
    // self-correcting afterwards)
    if (!fin && t >= 40 && ((t - 8) & 15) == 0 && r > 0.5f && r < 0.99f) {
      const float alpha = fminf(r / (1.0f - r), 25.0f);
#pragma unroll
      for (int a = 0; a < 4; ++a)
#pragma unroll
        for (int b = 0; b < 8; ++b) {
          const float g = prevG[a][b] + alpha * diff[a][b];
          sG[SWZ(i32 + a, j32 + b)] = g;
          prevG[a][b] = g;
        }
      __syncthreads();
    }
  }
}

// ---------------------------------------------------------------------------
// K1b: fold L_inf into constant step matrices.
// ---------------------------------------------------------------------------
__global__ __launch_bounds__(64, 1)
void lkf_fuse(const float* __restrict__ F, const float* __restrict__ Wfu,
              const float* __restrict__ Wfd, const float* __restrict__ Wy,
              const float* __restrict__ bfx, const float* __restrict__ bfu,
              const float* __restrict__ bfd, const float* __restrict__ bfy,
              const float* __restrict__ Linf, float* __restrict__ Az,
              float* __restrict__ Buz, float* __restrict__ Bdz,
              float* __restrict__ cz)
{
  __shared__ float srow[NXX];
  __shared__ float fw[NYY];
  const int w = blockIdx.x, tid = threadIdx.x;

  for (int k = tid; k < NXX; k += 64) {
    float v;
    if (w < 128)      v = F[w * NXX + k];
    else if (w < 160) v = Wfu[(w - 128) * NXX + k];
    else if (w < 176) v = Wfd[(w - 160) * NXX + k];
    else              v = bfx[k] + bfu[k] + bfd[k];
    srow[k] = v;
  }
  __syncthreads();
  {
    const int m = tid;
    float acc = (w == 176) ? bfy[m] : 0.f;
    for (int k = 0; k < NXX; ++k) acc += srow[k] * Wy[k * NYY + m];
    fw[m] = acc;
  }
  __syncthreads();
  for (int j = tid; j < NXX; j += 64) {
    float s = 0.f;
    for (int m = 0; m < NYY; ++m) s += fw[m] * Linf[j * NYY + m];
    const float val = srow[j] - s;
    if (w < 128)      Az[w * NXX + j] = val;
    else if (w < 160) Buz[(w - 128) * NXX + j] = val;
    else if (w < 176) Bdz[(w - 160) * NXX + j] = val;
    else              cz[j] = val;
  }
}

// ---------------------------------------------------------------------------
// K1c: 128x128 matrix squaring (for A^64 via 6 repeated squarings).
// ---------------------------------------------------------------------------
__global__ __launch_bounds__(256, 1)
void mat_sq(const float* __restrict__ in, float* __restrict__ out)
{
  const int gid = blockIdx.x * 256 + threadIdx.x;  // grid 64 -> 16384 = 128*128
  const int i = gid >> 7, j = gid & 127;
  float acc = 0.f;
  for (int k = 0; k < NXX; ++k) acc += in[i * NXX + k] * in[k * NXX + j];
  out[gid] = acc;
}

// ---------------------------------------------------------------------------
// K2a: time-parallel chunk pass.  v <- v A + i_t over 64 steps (v_0 = 0),
// i_t = ym_t L^T + u_t Bu + d_t Bd + c.  8192 independent blocks.
// Layout this round: 256 threads = 64 col-pairs x 4 k-groups.  Each thread
// owns cols (q, q+64) and a QUARTER of k -> per-step LDS broadcasts halve
// (30 -> 15 b128/thread) and FMA/b128 doubles (4 -> 8).  3-way partial
// reduction via LDS.  All chunk inputs LDS-staged up front (28 KB).
// ---------------------------------------------------------------------------
__global__ __launch_bounds__(256, 2)
void lkf_chunk(const float* __restrict__ Yp, const float* __restrict__ Up,
               const float* __restrict__ Dp, const float* __restrict__ Az,
               const float* __restrict__ Buz, const float* __restrict__ Bdz,
               const float* __restrict__ cz, const float* __restrict__ LinfT,
               float* __restrict__ V)
{
  __shared__ __align__(16) float4 inL[1792];      // ym 1024 | u 512 | d 256 (28 KB)
  __shared__ __align__(16) float xs[2][NXX];
  __shared__ float ps[3 * NXX];

  const int tid = threadIdx.x;
  const int b   = blockIdx.x;       // batch
  const int c   = blockIdx.y;       // chunk
  const int q   = tid & 63;         // col-pair index
  const int h   = tid >> 6;         // k-quarter (0..3)
  const int j0  = q;
  const int j1  = q + 64;

  // constants: cols j0,j1, k-range [h*32,h*32+32) etc.
  float a0[32], a1[32], l0[16], l1[16], bu0[8], bu1[8], bd0[4], bd1[4];
#pragma unroll
  for (int k = 0; k < 32; ++k) {
    a0[k] = Az[(h * 32 + k) * NXX + j0];
    a1[k] = Az[(h * 32 + k) * NXX + j1];
  }
#pragma unroll
  for (int m = 0; m < 16; ++m) {
    l0[m] = LinfT[(h * 16 + m) * NXX + j0];
    l1[m] = LinfT[(h * 16 + m) * NXX + j1];
  }
#pragma unroll
  for (int k = 0; k < 8; ++k) {
    bu0[k] = Buz[(h * 8 + k) * NXX + j0];
    bu1[k] = Buz[(h * 8 + k) * NXX + j1];
  }
#pragma unroll
  for (int k = 0; k < 4; ++k) {
    bd0[k] = Bdz[(h * 4 + k) * NXX + j0];
    bd1[k] = Bdz[(h * 4 + k) * NXX + j1];
  }
  const float cj0 = (h == 0) ? cz[j0] : 0.f;
  const float cj1 = (h == 0) ? cz[j1] : 0.f;

  const int t0 = c * CCH;
  // ---- stage the whole chunk's inputs (7 coalesced float4 per thread) ----
  {
    const float4* Y4 = (const float4*)Yp;
    const float4* U4 = (const float4*)Up;
    const float4* D4 = (const float4*)Dp;
#pragma unroll
    for (int e = 0; e < 7; ++e) {
      const int idx = e * 256 + tid;
      float4 v;
      if (e < 4) {                       // ym region: idx in [0,1024)
        const int s = idx >> 4, f = idx & 15;
        v = Y4[((size_t)(t0 + s) * BATCH + b) * (NYY / 4) + f];
      } else if (e < 6) {                // u region: idx in [1024,1536)
        const int rel = idx - 1024, s = rel >> 3, f = rel & 7;
        v = U4[((size_t)(t0 + s) * BATCH + b) * (NUU / 4) + f];
      } else {                           // d region: idx in [1536,1792)
        const int rel = idx - 1536, s = rel >> 2, f = rel & 3;
        v = D4[((size_t)(t0 + s) * BATCH + b) * (NDD / 4) + f];
      }
      inL[idx] = v;
    }
  }
  if (tid < 128) xs[0][tid] = 0.f;
  __syncthreads();

  for (int s = 0; s < CCH; ++s) {
    const int p = s & 1;
    float p00 = cj0, p01 = 0.f, p02 = 0.f, p03 = 0.f;
    float p10 = cj1, p11 = 0.f, p12 = 0.f, p13 = 0.f;
    {
      const float4* x4 = (const float4*)(xs[p] + h * 32);
#pragma unroll
      for (int k4 = 0; k4 < 8; ++k4) {
        const float4 xv = x4[k4];
        p00 += xv.x * a0[4 * k4 + 0];
        p01 += xv.y * a0[4 * k4 + 1];
        p02 += xv.z * a0[4 * k4 + 2];
        p03 += xv.w * a0[4 * k4 + 3];
        p10 += xv.x * a1[4 * k4 + 0];
        p11 += xv.y * a1[4 * k4 + 1];
        p12 += xv.z * a1[4 * k4 + 2];
        p13 += xv.w * a1[4 * k4 + 3];
      }
      const float4* y4 = inL + s * 16 + h * 4;
#pragma unroll
      for (int m4 = 0; m4 < 4; ++m4) {
        const float4 yv = y4[m4];
        p00 += yv.x * l0[4 * m4 + 0];
        p01 += yv.y * l0[4 * m4 + 1];
        p02 += yv.z * l0[4 * m4 + 2];
        p03 += yv.w * l0[4 * m4 + 3];
        p10 += yv.x * l1[4 * m4 + 0];
        p11 += yv.y * l1[4 * m4 + 1];
        p12 += yv.z * l1[4 * m4 + 2];
        p13 += yv.w * l1[4 * m4 + 3];
      }
      const float4* u4 = inL + 1024 + s * 8 + h * 2;
#pragma unroll
      for (int k4 = 0; k4 < 2; ++k4) {
        const float4 uv = u4[k4];
        p00 += uv.x * bu0[4 * k4 + 0];
        p01 += uv.y * bu0[4 * k4 + 1];
        p02 += uv.z * bu0[4 * k4 + 2];
        p03 += uv.w * bu0[4 * k4 + 3];
        p10 += uv.x * bu1[4 * k4 + 0];
        p11 += uv.y * bu1[4 * k4 + 1];
        p12 += uv.z * bu1[4 * k4 + 2];
        p13 += uv.w * bu1[4 * k4 + 3];
      }
      {
        const float4 dv = inL[1536 + s * 4 + h];
        p00 += dv.x * bd0[0];
        p01 += dv.y * bd0[1];
        p02 += dv.z * bd0[2];
        p03 += dv.w * bd0[3];
        p10 += dv.x * bd1[0];
        p11 += dv.y * bd1[1];
        p12 += dv.z * bd1[2];
        p13 += dv.w * bd1[3];
      }
    }
    const float part0 = (p00 + p01) + (p02 + p03);
    const float part1 = (p10 + p11) + (p12 + p13);
    if (h > 0) {
      ps[(h - 1) * NXX + j0] = part0;
      ps[(h - 1) * NXX + j1] = part1;
    }
    __syncthreads();
    if (h == 0) {
      xs[1 - p][j0] = part0 + ps[j0] + ps[NXX + j0] + ps[2 * NXX + j0];
      xs[1 - p][j1] = part1 + ps[j1] + ps[NXX + j1] + ps[2 * NXX + j1];
    }
    __syncthreads();
  }

  if (tid < 128)
    V[((size_t)b * NCH + c) * NXX + tid] = xs[0][tid];   // CCH even -> xs[0]
}

// ---------------------------------------------------------------------------
// K2b: serial chunk combine:  x <- x A^64 + v_c,  c = 0..NCH-1; out = x.
// ---------------------------------------------------------------------------
__global__ __launch_bounds__(128, 1)
void lkf_comb(const float* __restrict__ A64, const float* __restrict__ V,
              const float* __restrict__ x0, float* __restrict__ out)
{
  __shared__ __align__(16) float xs[2][NXX];
  const int tid = threadIdx.x;
  const int b   = blockIdx.x;
  float a[NXX];
#pragma unroll
  for (int k = 0; k < NXX; ++k) a[k] = A64[k * NXX + tid];
  xs[0][tid] = x0[tid];
  __syncthreads();
  for (int c = 0; c < NCH; ++c) {
    const int p = c & 1;
    float acc0 = V[((size_t)b * NCH + c) * NXX + tid];
    float acc1 = 0.f, acc2 = 0.f, acc3 = 0.f;
    const float4* x4 = (const float4*)xs[p];
#pragma unroll
    for (int k4 = 0; k4 < NXX / 4; ++k4) {
      const float4 xv = x4[k4];
      acc0 += xv.x * a[4 * k4 + 0];
      acc1 += xv.y * a[4 * k4 + 1];
      acc2 += xv.z * a[4 * k4 + 2];
      acc3 += xv.w * a[4 * k4 + 3];
    }
    xs[1 - p][tid] = (acc0 + acc1) + (acc2 + acc3);
    __syncthreads();
  }
  out[(size_t)b * NXX + tid] = xs[0][tid];   // NCH even -> xs[0]
}

// ---------------------------------------------------------------------------
// K2 (fallback): fully serial state recursion; used only when the workspace
// is too small for the chunk path.
// ---------------------------------------------------------------------------
__global__ __launch_bounds__(128, 1)
void lkf_state(const float* __restrict__ Yp, const float* __restrict__ Up,
               const float* __restrict__ Dp, const float* __restrict__ Az,
               const float* __restrict__ Buz, const float* __restrict__ Bdz,
               const float* __restrict__ cz, const float* __restrict__ LinfT,
               const float* __restrict__ x0, float* __restrict__ out)
{
  __shared__ __align__(16) float xs[2][NXX];
  __shared__ __align__(16) float ymb[2][NYY];
  __shared__ __align__(16) float ub[2][NUU];
  __shared__ __align__(16) float db[2][NDD];

  const int tid = threadIdx.x;
  const int b   = blockIdx.x;
  const int j   = tid;

  float a[NXX], l[NYY], bu[NUU], bd[NDD];
#pragma unroll
  for (int k = 0; k < NXX; ++k) a[k] = Az[k * NXX + j];
#pragma unroll
  for (int m = 0; m < NYY; ++m) l[m] = LinfT[m * NXX + j];
#pragma unroll
  for (int k = 0; k < NUU; ++k) bu[k] = Buz[k * NXX + j];
#pragma unroll
  for (int k = 0; k < NDD; ++k) bd[k] = Bdz[k * NXX + j];
  const float cj = cz[j];

  xs[0][tid] = x0[tid];
  if (tid < 64)       ymb[0][tid]     = Yp[(size_t)b * NYY + tid];
  else if (tid < 96)  ub[0][tid - 64] = Up[(size_t)b * NUU + (tid - 64)];
  else if (tid < 112) db[0][tid - 96] = Dp[(size_t)b * NDD + (tid - 96)];
  __syncthreads();

  for (int t = 0; t < T_STEPS; ++t) {
    const int p = t & 1;
    float pf = 0.f;
    if (t < T_STEPS - 1) {
      const size_t tb = (size_t)(t + 1) * BATCH + b;
      if (tid < 64)       pf = Yp[tb * NYY + tid];
      else if (tid < 96)  pf = Up[tb * NUU + (tid - 64)];
      else if (tid < 112) pf = Dp[tb * NDD + (tid - 96)];
    }

    float acc0 = cj, acc1 = 0.f, acc2 = 0.f, acc3 = 0.f;
    {
      const float4* x4 = (const float4*)xs[p];
#pragma unroll
      for (int k4 = 0; k4 < NXX / 4; ++k4) {
        const float4 xv = x4[k4];
        acc0 += xv.x * a[4 * k4 + 0];
        acc1 += xv.y * a[4 * k4 + 1];
        acc2 += xv.z * a[4 * k4 + 2];
        acc3 += xv.w * a[4 * k4 + 3];
      }
      const float4* y4 = (const float4*)ymb[p];
#pragma unroll
      for (int m4 = 0; m4 < NYY / 4; ++m4) {
        const float4 yv = y4[m4];
        acc0 += yv.x * l[4 * m4 + 0];
        acc1 += yv.y * l[4 * m4 + 1];
        acc2 += yv.z * l[4 * m4 + 2];
        acc3 += yv.w * l[4 * m4 + 3];
      }
      const float4* u4 = (const float4*)ub[p];
#pragma unroll
      for (int k4 = 0; k4 < NUU / 4; ++k4) {
        const float4 uv = u4[k4];
        acc0 += uv.x * bu[4 * k4 + 0];
        acc1 += uv.y * bu[4 * k4 + 1];
        acc2 += uv.z * bu[4 * k4 + 2];
        acc3 += uv.w * bu[4 * k4 + 3];
      }
      const float4* d4 = (const float4*)db[p];
#pragma unroll
      for (int k4 = 0; k4 < NDD / 4; ++k4) {
        const float4 dv = d4[k4];
        acc0 += dv.x * bd[4 * k4 + 0];
        acc1 += dv.y * bd[4 * k4 + 1];
        acc2 += dv.z * bd[4 * k4 + 2];
        acc3 += dv.w * bd[4 * k4 + 3];
      }
    }
    xs[1 - p][j] = (acc0 + acc1) + (acc2 + acc3);

    if (t < T_STEPS - 1) {
      if (tid < 64)       ymb[1 - p][tid]     = pf;
      else if (tid < 96)  ub[1 - p][tid - 64] = pf;
      else if (tid < 112) db[1 - p][tid - 96] = pf;
    }
    __syncthreads();
  }

  out[(size_t)b * NXX + j] = xs[0][j];
}

// ---------------------------------------------------------------------------
extern "C" void kernel_launch(void* const* d_in, const int* in_sizes, int n_in,
                              void* d_out, int out_size, void* d_ws,
                              size_t ws_size, hipStream_t stream) {
  const float* Yp  = (const float*)d_in[0];
  const float* Up  = (const float*)d_in[1];
  const float* Dp  = (const float*)d_in[2];
  const float* Wfx = (const float*)d_in[3];
  const float* bfx = (const float*)d_in[4];
  const float* Wfu = (const float*)d_in[5];
  const float* bfu = (const float*)d_in[6];
  const float* Wfd = (const float*)d_in[7];
  const float* bfd = (const float*)d_in[8];
  const float* Wfy = (const float*)d_in[9];
  const float* bfy = (const float*)d_in[10];
  const float* Q   = (const float*)d_in[11];
  const float* R   = (const float*)d_in[12];
  const float* P0  = (const float*)d_in[13];
  const float* x0  = (const float*)d_in[15];

  float* ws    = (float*)d_ws;
  float* Linf  = ws;                      // 128*64
  float* LinfT = Linf  + NXX * NYY;       // 64*128
  float* CWq   = LinfT + NYY * NXX;       // 128*64
  float* tmpA  = CWq   + NXX * NYY;       // 128*128
  float* tmpB  = tmpA  + NXX * NXX;       // 128*128
  float* Az    = tmpB  + NXX * NXX;       // 128*128
  float* Buz   = Az    + NXX * NXX;       // 32*128
  float* Bdz   = Buz   + NUU * NXX;       // 16*128
  float* cz    = Bdz   + NDD * NXX;       // 128
  float* pA    = cz    + NXX;             // 128*128 (A^2k ping)
  float* pB    = pA    + NXX * NXX;       // 128*128 (A^2k pong)
  float* V     = pB    + NXX * NXX;       // 256*32*128 = 4 MB

  const size_t needBytes =
      ((size_t)(V - ws) + (size_t)BATCH * NCH * NXX) * sizeof(float);

  lkf_gains<<<dim3(1), dim3(256), 0, stream>>>(Wfx, Wfy, Q, R, P0, Linf, LinfT,
                                               CWq, tmpA, tmpB);
  lkf_fuse<<<dim3(177), dim3(64), 0, stream>>>(Wfx, Wfu, Wfd, Wfy, bfx, bfu,
                                               bfd, bfy, Linf, Az, Buz, Bdz,
                                               cz);

  if (ws_size >= needBytes) {
    // A^64 by repeated squaring: Az->pA (A^2), ... , pA->pB (A^64)
    mat_sq<<<dim3(64), dim3(256), 0, stream>>>(Az, pA);
    mat_sq<<<dim3(64), dim3(256), 0, stream>>>(pA, pB);
    mat_sq<<<dim3(64), dim3(256), 0, stream>>>(pB, pA);
    mat_sq<<<dim3(64), dim3(256), 0, stream>>>(pA, pB);
    mat_sq<<<dim3(64), dim3(256), 0, stream>>>(pB, pA);
    mat_sq<<<dim3(64), dim3(256), 0, stream>>>(pA, pB);   // pB = A^64
    lkf_chunk<<<dim3(BATCH, NCH), dim3(256), 0, stream>>>(
        Yp, Up, Dp, Az, Buz, Bdz, cz, LinfT, V);
    lkf_comb<<<dim3(BATCH), dim3(128), 0, stream>>>(pB, V, x0, (float*)d_out);
  } else {
    lkf_state<<<dim3(BATCH), dim3(128), 0, stream>>>(
        Yp, Up, Dp, Az, Buz, Bdz, cz, LinfT, x0, (float*)d_out);
  }
}